// Round 3
// baseline (575.105 us; speedup 1.0000x reference)
//
#include <hip/hip_runtime.h>
#include <hip/hip_bf16.h>
#include <math.h>
#include <type_traits>

// Problem constants (B=2, S=1024, DM=1024, QH=16, KVH=4)
constexpr int B_   = 2;
constexpr int S_   = 1024;
constexpr int DM_  = 1024;
constexpr int QH_  = 16;
constexpr int KVH_ = 4;
constexpr int DH_  = 64;
constexpr int DHH_ = 32;
constexpr int M_   = 32;    // sqrt(S)
constexpr int TOPK_ = 8;
constexpr int BS_  = B_ * S_;                    // 2048
constexpr int NW_  = QH_*DH_ + 2*KVH_*DH_;       // 1536 (q|k|v fused row)
constexpr int KOFF_ = QH_*DH_;                   // 1024
constexpr int VOFF_ = KOFF_ + KVH_*DH_;          // 1280

// ---------------------------------------------------------------------------
// GEMM: C[M][N] = A[M][K] @ W[N][K]^T. W split across 2 arrays at column n1.
// DACC=true -> f64 accumulation (score path: q,k kept ~exact so my side of
// every top-k comparison carries no accumulation noise).
// Tile 128x64, 256 threads, 8x4 micro-tile, K-tile 16.
// ---------------------------------------------------------------------------
constexpr int GBM = 128, GBN = 64, GBK = 16;

template<bool DACC>
__global__ __launch_bounds__(256) void gemm_kernel(
    const float* __restrict__ A,
    const float* __restrict__ W0, const float* __restrict__ W1,
    int n1,
    float* __restrict__ C, int N, int K)
{
    using AccT = typename std::conditional<DACC, double, float>::type;
    __shared__ __align__(16) float As[GBK][GBM];   // transposed: [k][row]
    __shared__ __align__(16) float Ws[GBK][GBN];   // transposed: [k][col]
    const int tid = threadIdx.x;
    const int rowBase = blockIdx.x * GBM;
    const int colBase = blockIdx.y * GBN;
    const int tr = tid & 15;   // row group (8 rows)
    const int tc = tid >> 4;   // col group (4 cols)

    AccT acc[8][4] = {};

    for (int k0 = 0; k0 < K; k0 += GBK) {
        // ---- stage A tile: 128x16 = 512 float4 slots, 2 per thread
#pragma unroll
        for (int t = 0; t < 2; ++t) {
            int slot = tid + t * 256;
            int arow = slot >> 2;
            int kc   = (slot & 3) << 2;
            float4 v = *reinterpret_cast<const float4*>(
                &A[(size_t)(rowBase + arow) * K + k0 + kc]);
            As[kc+0][arow] = v.x; As[kc+1][arow] = v.y;
            As[kc+2][arow] = v.z; As[kc+3][arow] = v.w;
        }
        // ---- stage W tile: 64x16 = 256 float4 slots, 1 per thread
        {
            int wcol = tid >> 2;
            int kc   = (tid & 3) << 2;
            int n = colBase + wcol;
            const float* wr = (n < n1) ? (W0 + (size_t)n * K)
                                       : (W1 + (size_t)(n - n1) * K);
            float4 v = *reinterpret_cast<const float4*>(&wr[k0 + kc]);
            Ws[kc+0][wcol] = v.x; Ws[kc+1][wcol] = v.y;
            Ws[kc+2][wcol] = v.z; Ws[kc+3][wcol] = v.w;
        }
        __syncthreads();
#pragma unroll
        for (int kk = 0; kk < GBK; ++kk) {
            float4 a0 = *reinterpret_cast<const float4*>(&As[kk][tr*8]);
            float4 a1 = *reinterpret_cast<const float4*>(&As[kk][tr*8+4]);
            float4 wv = *reinterpret_cast<const float4*>(&Ws[kk][tc*4]);
            float a[8] = {a0.x,a0.y,a0.z,a0.w,a1.x,a1.y,a1.z,a1.w};
            float wj[4] = {wv.x,wv.y,wv.z,wv.w};
#pragma unroll
            for (int i = 0; i < 8; ++i)
#pragma unroll
                for (int j = 0; j < 4; ++j) {
                    if constexpr (DACC)
                        acc[i][j] = fma((double)a[i], (double)wj[j], acc[i][j]);
                    else
                        acc[i][j] = fmaf(a[i], wj[j], acc[i][j]);
                }
        }
        __syncthreads();
    }
#pragma unroll
    for (int i = 0; i < 8; ++i) {
        float4 v = make_float4((float)acc[i][0], (float)acc[i][1],
                               (float)acc[i][2], (float)acc[i][3]);
        *reinterpret_cast<float4*>(
            &C[(size_t)(rowBase + tr*8 + i) * N + colBase + tc*4]) = v;
    }
}

// ---------------------------------------------------------------------------
// RoPE in-place, bit-matching the numpy f32 reference:
//   inv_freq = 1.0f / powf(10000f, d/32f)   <- TWO f32 roundings (pow, then
//     divide). Round 1/2 used (float)(1.0/pow_f64) = ONE rounding; the 1-ulp
//     inv_freq differences are amplified by s (up to 1023x) into ~1e-4 angle
//     discrepancies -> deterministic top-k flips (the bit-identical 0.048
//     absmax across rounds 1 and 2).
//   ang = f32(s) * inv_freq (f32 multiply).
//   sin/cos: f64 sincos of the f32 angle, rounded to f32 == correctly-rounded
//     sinf/cosf (glibc).
//   rotation in strict f32, NO fma contraction (numpy does mul, mul, add).
// ---------------------------------------------------------------------------
__global__ __launch_bounds__(256) void rope_kernel(float* __restrict__ qkv)
{
    int id = blockIdx.x * 256 + threadIdx.x;   // BS * 20 * 32 threads
    int d  = id & 31;
    int r  = id >> 5;
    int h  = r % (QH_ + KVH_);
    int bs = r / (QH_ + KVH_);
    int s  = bs & (S_ - 1);
    float* base = qkv + (size_t)bs * NW_ +
                  (h < QH_ ? h * DH_ : KOFF_ + (h - QH_) * DH_);
    double e = (double)d * (1.0 / 32.0);
    float pf = (float)pow(10000.0, e);         // == correctly-rounded powf
    float inv_freq = __fdiv_rn(1.0f, pf);      // f32 divide (numpy's 2nd rounding)
    float ang = __fmul_rn((float)s, inv_freq); // f32 multiply: matches ref
    double sn64, cs64;
    sincos((double)ang, &sn64, &cs64);
    float cs = (float)cs64;                    // == correctly-rounded cosf
    float sn = (float)sn64;
    float x1 = base[d];
    float x2 = base[d + DHH_];
    // x*cos + rot*sin, strict f32, no FMA (matches numpy elementwise ops)
    base[d]        = __fadd_rn(__fmul_rn(x1, cs), __fmul_rn(-x2, sn));
    base[d + DHH_] = __fadd_rn(__fmul_rn(x2, cs), __fmul_rn(x1, sn));
}

// ---------------------------------------------------------------------------
// k1[b,kv,m,d<32] = sum_mc k_rope[b, m*32+mc, kv, d]        (f64 accumulate)
// k2[b,kv,m,d<32] = sum_mr k_rope[b, mr*32+m, kv, 32+d]
// ---------------------------------------------------------------------------
__global__ __launch_bounds__(256) void k1k2_kernel(
    const float* __restrict__ qkv, double* __restrict__ k1,
    double* __restrict__ k2)
{
    int blk = blockIdx.x;            // b*KVH + kv  (8 blocks)
    int b = blk >> 2, kv = blk & 3;
    int tid = threadIdx.x;
    int d = tid & 31;
    const float* kbase = qkv + (size_t)b * S_ * NW_ + KOFF_ + kv * DH_;
    for (int m = tid >> 5; m < M_; m += 8) {
        double s1 = 0., s2 = 0.;
        for (int mc = 0; mc < M_; ++mc) {
            s1 += (double)kbase[(size_t)(m * M_ + mc) * NW_ + d];
            s2 += (double)kbase[(size_t)(mc * M_ + m) * NW_ + DHH_ + d];
        }
        k1[((b * KVH_ + kv) * M_ + m) * DHH_ + d] = s1;
        k2[((b * KVH_ + kv) * M_ + m) * DHH_ + d] = s2;
    }
}

// ---------------------------------------------------------------------------
// Select + attention kernel, f64 score path. One wave per (b,h,s); block = 4
// waves covering 4 consecutive s of one (b,h); k1/k2 staged once in LDS.
// Stage 1: s1[m]=q1.k1[m] (lanes 0-31), s2[m]=q2.k2[m] (lanes 32-63),
// iterative shuffle top-8 per half (max value, lowest index == jax top_k).
// Stage 2: 64 combined scores a_i+b_j == q.cand (exact algebraic identity),
// full-wave top-8, softmax(scores/8), out[d] = sum_t w_t * v[row*32+col][d].
// ---------------------------------------------------------------------------
__global__ __launch_bounds__(256) void select_kernel(
    const float* __restrict__ qkv,
    const double* __restrict__ k1g, const double* __restrict__ k2g,
    float* __restrict__ aout)
{
    __shared__ double k1s[M_][DHH_ + 1];   // +1 pad: conflict-free row reads
    __shared__ double k2s[M_][DHH_ + 1];
    __shared__ float  qs[4][DH_];
    __shared__ double abuf[4][TOPK_], bbuf[4][TOPK_];
    __shared__ int    i1buf[4][TOPK_], i2buf[4][TOPK_];

    const int tid = threadIdx.x;
    const int bh  = blockIdx.x >> 8;           // S/4 = 256 blocks per (b,h)
    const int s0  = (blockIdx.x & 255) << 2;
    const int b   = bh >> 4;
    const int h   = bh & 15;
    const int kv  = h >> 2;                    // n_rep = 4

    // stage k1/k2 (1024 doubles each)
    const int kbase = (b * KVH_ + kv) * M_ * DHH_;
    for (int i = tid; i < M_ * DHH_; i += 256) {
        k1s[i >> 5][i & 31] = k1g[kbase + i];
        k2s[i >> 5][i & 31] = k2g[kbase + i];
    }

    const int w    = tid >> 6;
    const int lane = tid & 63;
    const int s    = s0 + w;
    const float* qrow = qkv + (size_t)(b * S_ + s) * NW_ + h * DH_;
    qs[w][lane] = qrow[lane];
    __syncthreads();

    // ---- stage-1 dots (f64)
    const int m = lane & 31;
    const bool hi = lane >= 32;
    double dot = 0.;
    {
        const double* krow = hi ? &k2s[m][0] : &k1s[m][0];
        const float*  qq   = &qs[w][hi ? DHH_ : 0];
#pragma unroll
        for (int d = 0; d < DHH_; ++d)
            dot = fma((double)qq[d], krow[d], dot);
    }

    // ---- top-8 within each 32-lane half (value desc, index asc on ties)
    double val = dot; int idx = m;
#pragma unroll
    for (int t = 0; t < TOPK_; ++t) {
        double bv = val; int bi = idx;
#pragma unroll
        for (int msk = 1; msk <= 16; msk <<= 1) {
            double ov = __shfl_xor(bv, msk);
            int    oi = __shfl_xor(bi, msk);
            if (ov > bv || (ov == bv && oi < bi)) { bv = ov; bi = oi; }
        }
        if (lane == t)      { abuf[w][t] = bv; i1buf[w][t] = bi; }
        if (lane == 32 + t) { bbuf[w][t] = bv; i2buf[w][t] = bi; }
        if (idx == bi) val = -__builtin_huge_val();
    }
    __syncthreads();

    // ---- stage-2: 64 combined scores, full-wave top-8
    double cval = abuf[w][lane >> 3] + bbuf[w][lane & 7];
    double sv[TOPK_]; int sel[TOPK_];
    double val2 = cval; int idx2 = lane;
#pragma unroll
    for (int t = 0; t < TOPK_; ++t) {
        double bv = val2; int bi = idx2;
#pragma unroll
        for (int msk = 1; msk <= 32; msk <<= 1) {
            double ov = __shfl_xor(bv, msk);
            int    oi = __shfl_xor(bi, msk);
            if (ov > bv || (ov == bv && oi < bi)) { bv = ov; bi = oi; }
        }
        sv[t] = bv; sel[t] = bi;
        if (idx2 == bi) val2 = -__builtin_huge_val();
    }

    // ---- softmax over 8 (scores/8, max-subtracted) + weighted v gather
    double wex[TOPK_]; double wsum = 0.;
#pragma unroll
    for (int t = 0; t < TOPK_; ++t) {
        wex[t] = exp((sv[t] - sv[0]) * 0.125);
        wsum += wex[t];
    }
    const double inv = 1.0 / wsum;
    double o = 0.;
#pragma unroll
    for (int t = 0; t < TOPK_; ++t) {
        int row = i1buf[w][sel[t] >> 3];
        int col = i2buf[w][sel[t] & 7];
        float vvv = qkv[(size_t)(b * S_ + row * M_ + col) * NW_ +
                        VOFF_ + kv * DH_ + lane];
        o = fma(wex[t] * inv, (double)vvv, o);
    }
    aout[(size_t)(b * S_ + s) * (QH_ * DH_) + h * DH_ + lane] = (float)o;
}

// ---------------------------------------------------------------------------
extern "C" void kernel_launch(void* const* d_in, const int* in_sizes, int n_in,
                              void* d_out, int out_size, void* d_ws,
                              size_t ws_size, hipStream_t stream)
{
    const float* x  = (const float*)d_in[0];
    const float* wq = (const float*)d_in[1];
    const float* wk = (const float*)d_in[2];
    const float* wv = (const float*)d_in[3];
    const float* wo = (const float*)d_in[4];
    float* out = (float*)d_out;

    // workspace layout: qkv f32 | k1 f64 | k2 f64 | attn_out f32  (~21 MB)
    float*  wsf  = (float*)d_ws;
    float*  qkv  = wsf;                                  // 2048*1536 f32
    double* k1   = (double*)(qkv + (size_t)BS_ * NW_);   // 8192 f64
    double* k2   = k1 + B_ * KVH_ * M_ * DHH_;           // 8192 f64
    float*  aout = (float*)(k2 + B_ * KVH_ * M_ * DHH_); // 2048*1024 f32

    // 1a) q|k GEMM (cols [0,1280)), f64 accumulation
    dim3 gqk(BS_ / GBM, VOFF_ / GBN);
    gemm_kernel<true><<<gqk, 256, 0, stream>>>(x, wq, wk, KOFF_,
                                               qkv, NW_, DM_);
    // 1b) v GEMM (cols [1280,1536)), f32
    dim3 gv(BS_ / GBM, (NW_ - VOFF_) / GBN);
    gemm_kernel<false><<<gv, 256, 0, stream>>>(x, wv, wv, 1 << 30,
                                               qkv + VOFF_, NW_, DM_);
    // 2) RoPE on q,k (numpy-f32 bit-matched)
    rope_kernel<<<(BS_ * (QH_ + KVH_) * DHH_) / 256, 256, 0, stream>>>(qkv);
    // 3) k1/k2 grid sums (f64)
    k1k2_kernel<<<B_ * KVH_, 256, 0, stream>>>(qkv, k1, k2);
    // 4) two-stage top-k select + 8-key attention (f64 score path)
    select_kernel<<<B_ * QH_ * S_ / 4, 256, 0, stream>>>(qkv, k1, k2, aout);
    // 5) output GEMM: out = attn_out @ wo^T (f32)
    dim3 go(BS_ / GBM, DM_ / GBN);
    gemm_kernel<false><<<go, 256, 0, stream>>>(aout, wo, wo, 1 << 30,
                                               out, DM_, DM_);
}

// Round 4
// 260.537 us; speedup vs baseline: 2.2074x; 2.2074x over previous
//
#include <hip/hip_runtime.h>
#include <hip/hip_bf16.h>
#include <math.h>

// Problem constants (B=2, S=1024, DM=1024, QH=16, KVH=4)
constexpr int B_   = 2;
constexpr int S_   = 1024;
constexpr int DM_  = 1024;
constexpr int QH_  = 16;
constexpr int KVH_ = 4;
constexpr int DH_  = 64;
constexpr int DHH_ = 32;
constexpr int M_   = 32;    // sqrt(S)
constexpr int TOPK_ = 8;
constexpr int BS_  = B_ * S_;                    // 2048
constexpr int NW_  = QH_*DH_ + 2*KVH_*DH_;       // 1536 (q|k|v fused row)
constexpr int KOFF_ = QH_*DH_;                   // 1024
constexpr int VOFF_ = KOFF_ + KVH_*DH_;          // 1280

typedef __attribute__((ext_vector_type(8))) short short8v;   // 8 bf16 (4 VGPR)
typedef __attribute__((ext_vector_type(4))) short short4v;   // 4 bf16 (8B)
typedef __attribute__((ext_vector_type(4))) float float4v;   // MFMA acc

__device__ inline unsigned short bf16_rne(float f) {
    unsigned u = __float_as_uint(f);
    return (unsigned short)((u + 0x7FFFu + ((u >> 16) & 1u)) >> 16);
}
__device__ inline float bf16_back(unsigned short h) {
    return __uint_as_float(((unsigned)h) << 16);
}

// ---------------------------------------------------------------------------
// Split-bf16 MFMA GEMM: C[M][N] = A[M][K] @ W[N][K]^T, K=1024.
// Each f32 operand is split in-kernel into LEVELS bf16 terms (h1+h2+...);
// products h_la * g_lb with la+lb <= CROSS are accumulated via
// mfma_f32_16x16x32_bf16.  LEVELS=3/CROSS=2 (6 products): residual ~2^-24 ->
// score-path noise ~3e-6, 100x below the numpy reference's own f32 noise.
// LEVELS=2/CROSS=2 (4 products): residual ~2^-16 -> value-grade (v / out).
// Tile 128x128, 4 waves (2x2), BK=32, register-staged splits into
// XOR-swizzled LDS, next-chunk global prefetch overlapped with MFMA phase.
// Fragment layouts (gfx950, verified in guide): A: row=lane&15,
// k=(lane>>4)*8+j ; B symmetric ; C/D: col=lane&15, row=(lane>>4)*4+reg.
// ---------------------------------------------------------------------------
template<int LEVELS, int CROSS>
__global__ __launch_bounds__(256) void gemm_mfma_kernel(
    const float* __restrict__ A,
    const float* __restrict__ W0, const float* __restrict__ W1,
    const float* __restrict__ W2, int n1, int n2,
    float* __restrict__ C, int N, int K)
{
    __shared__ short As[LEVELS * 128 * 32];
    __shared__ short Bs[LEVELS * 128 * 32];
    const int tid = threadIdx.x;
    const int rowBase = blockIdx.x * 128;
    const int colBase = blockIdx.y * 128;
    const int lane = tid & 63, wv = tid >> 6;
    const int wr = wv >> 1, wc = wv & 1;       // wave tile origin /64
    const int fr = lane & 15, fk = lane >> 4;  // fragment row/col, k-group

    // --- staging slots: 1024 float4 per tile, 4 per thread (fixed row/c4)
    const float* aptr[4]; const float* bptr[4];
    int arow_[4], ac4_[4];
#pragma unroll
    for (int i = 0; i < 4; ++i) {
        int q = i * 256 + tid;
        int row = q >> 3, c4 = q & 7;
        arow_[i] = row; ac4_[i] = c4;
        aptr[i] = A + (size_t)(rowBase + row) * K + c4 * 4;
        int n = colBase + row;
        const float* wrow = (n < n1) ? W0 + (size_t)n * K
                          : (n < n2) ? W1 + (size_t)(n - n1) * K
                                     : W2 + (size_t)(n - n2) * K;
        bptr[i] = wrow + c4 * 4;
    }

    float4 pa[4], pb[4];
#pragma unroll
    for (int i = 0; i < 4; ++i) {
        pa[i] = *reinterpret_cast<const float4*>(aptr[i]);
        pb[i] = *reinterpret_cast<const float4*>(bptr[i]);
    }

    float4v acc[4][4];
#pragma unroll
    for (int mi = 0; mi < 4; ++mi)
#pragma unroll
        for (int ni = 0; ni < 4; ++ni) acc[mi][ni] = (float4v)0.f;

    const int NKC = K >> 5;
    for (int kc = 0; kc < NKC; ++kc) {
        // ---- split-convert + LDS write (XOR-4 swizzle keeps 8B/16B align)
#pragma unroll
        for (int i = 0; i < 4; ++i) {
            int row = arow_[i];
            int base = row * 64 + ((ac4_[i] * 8) ^ ((row & 3) << 4));
            float fa[4] = {pa[i].x, pa[i].y, pa[i].z, pa[i].w};
            float fb[4] = {pb[i].x, pb[i].y, pb[i].z, pb[i].w};
#pragma unroll
            for (int l = 0; l < LEVELS; ++l) {
                short4v sa, sb;
#pragma unroll
                for (int e = 0; e < 4; ++e) {
                    unsigned short ha = bf16_rne(fa[e]);
                    unsigned short hb = bf16_rne(fb[e]);
                    sa[e] = (short)ha; sb[e] = (short)hb;
                    fa[e] -= bf16_back(ha);
                    fb[e] -= bf16_back(hb);
                }
                *reinterpret_cast<short4v*>((char*)As + l * 8192 + base) = sa;
                *reinterpret_cast<short4v*>((char*)Bs + l * 8192 + base) = sb;
            }
        }
        __syncthreads();
        // ---- prefetch next chunk (overlaps with MFMA phase below)
        if (kc + 1 < NKC) {
#pragma unroll
            for (int i = 0; i < 4; ++i) {
                pa[i] = *reinterpret_cast<const float4*>(aptr[i] + (kc+1)*32);
                pb[i] = *reinterpret_cast<const float4*>(bptr[i] + (kc+1)*32);
            }
        }
        // ---- fragment loads + MFMA
        short8v aF[LEVELS][4];
#pragma unroll
        for (int l = 0; l < LEVELS; ++l)
#pragma unroll
            for (int mi = 0; mi < 4; ++mi) {
                int row = wr * 64 + mi * 16 + fr;
                int byte = l * 8192 + row * 64 + ((fk * 16) ^ ((row & 3) << 4));
                aF[l][mi] = *reinterpret_cast<const short8v*>((const char*)As + byte);
            }
#pragma unroll
        for (int lb = 0; lb < LEVELS; ++lb) {
            short8v bF[4];
#pragma unroll
            for (int ni = 0; ni < 4; ++ni) {
                int row = wc * 64 + ni * 16 + fr;
                int byte = lb * 8192 + row * 64 + ((fk * 16) ^ ((row & 3) << 4));
                bF[ni] = *reinterpret_cast<const short8v*>((const char*)Bs + byte);
            }
#pragma unroll
            for (int la = 0; la < LEVELS; ++la) {
                if (la + lb > CROSS) continue;
#pragma unroll
                for (int mi = 0; mi < 4; ++mi)
#pragma unroll
                    for (int ni = 0; ni < 4; ++ni)
                        acc[mi][ni] = __builtin_amdgcn_mfma_f32_16x16x32_bf16(
                            aF[la][mi], bF[ni], acc[mi][ni], 0, 0, 0);
            }
        }
        __syncthreads();
    }
    // ---- epilogue: C/D layout col=lane&15, row=(lane>>4)*4+j
#pragma unroll
    for (int mi = 0; mi < 4; ++mi)
#pragma unroll
        for (int ni = 0; ni < 4; ++ni) {
            int row0 = rowBase + wr * 64 + mi * 16 + fk * 4;
            int col  = colBase + wc * 64 + ni * 16 + fr;
#pragma unroll
            for (int j = 0; j < 4; ++j)
                C[(size_t)(row0 + j) * N + col] = acc[mi][ni][j];
        }
}

// ---------------------------------------------------------------------------
// RoPE in-place, bit-matching the numpy f32 reference (see round-3 notes:
// inv_freq needs numpy's TWO f32 roundings; f32 angle; f64 trig; strict-f32
// non-FMA rotation).
// ---------------------------------------------------------------------------
__global__ __launch_bounds__(256) void rope_kernel(float* __restrict__ qkv)
{
    int id = blockIdx.x * 256 + threadIdx.x;   // BS * 20 * 32 threads
    int d  = id & 31;
    int r  = id >> 5;
    int h  = r % (QH_ + KVH_);
    int bs = r / (QH_ + KVH_);
    int s  = bs & (S_ - 1);
    float* base = qkv + (size_t)bs * NW_ +
                  (h < QH_ ? h * DH_ : KOFF_ + (h - QH_) * DH_);
    double e = (double)d * (1.0 / 32.0);
    float pf = (float)pow(10000.0, e);         // == correctly-rounded powf
    float inv_freq = __fdiv_rn(1.0f, pf);      // numpy's 2nd f32 rounding
    float ang = __fmul_rn((float)s, inv_freq);
    double sn64, cs64;
    sincos((double)ang, &sn64, &cs64);
    float cs = (float)cs64;
    float sn = (float)sn64;
    float x1 = base[d];
    float x2 = base[d + DHH_];
    base[d]        = __fadd_rn(__fmul_rn(x1, cs), __fmul_rn(-x2, sn));
    base[d + DHH_] = __fadd_rn(__fmul_rn(x2, cs), __fmul_rn(x1, sn));
}

// ---------------------------------------------------------------------------
// k1/k2 grid sums (f64 accumulate)
// ---------------------------------------------------------------------------
__global__ __launch_bounds__(256) void k1k2_kernel(
    const float* __restrict__ qkv, double* __restrict__ k1,
    double* __restrict__ k2)
{
    int blk = blockIdx.x;            // b*KVH + kv  (8 blocks)
    int b = blk >> 2, kv = blk & 3;
    int tid = threadIdx.x;
    int d = tid & 31;
    const float* kbase = qkv + (size_t)b * S_ * NW_ + KOFF_ + kv * DH_;
    for (int m = tid >> 5; m < M_; m += 8) {
        double s1 = 0., s2 = 0.;
        for (int mc = 0; mc < M_; ++mc) {
            s1 += (double)kbase[(size_t)(m * M_ + mc) * NW_ + d];
            s2 += (double)kbase[(size_t)(mc * M_ + m) * NW_ + DHH_ + d];
        }
        k1[((b * KVH_ + kv) * M_ + m) * DHH_ + d] = s1;
        k2[((b * KVH_ + kv) * M_ + m) * DHH_ + d] = s2;
    }
}

// ---------------------------------------------------------------------------
// Select + attention (f64 score path), unchanged from round 3 (known-good).
// ---------------------------------------------------------------------------
__global__ __launch_bounds__(256) void select_kernel(
    const float* __restrict__ qkv,
    const double* __restrict__ k1g, const double* __restrict__ k2g,
    float* __restrict__ aout)
{
    __shared__ double k1s[M_][DHH_ + 1];
    __shared__ double k2s[M_][DHH_ + 1];
    __shared__ float  qs[4][DH_];
    __shared__ double abuf[4][TOPK_], bbuf[4][TOPK_];
    __shared__ int    i1buf[4][TOPK_], i2buf[4][TOPK_];

    const int tid = threadIdx.x;
    const int bh  = blockIdx.x >> 8;
    const int s0  = (blockIdx.x & 255) << 2;
    const int b   = bh >> 4;
    const int h   = bh & 15;
    const int kv  = h >> 2;

    const int kbase = (b * KVH_ + kv) * M_ * DHH_;
    for (int i = tid; i < M_ * DHH_; i += 256) {
        k1s[i >> 5][i & 31] = k1g[kbase + i];
        k2s[i >> 5][i & 31] = k2g[kbase + i];
    }

    const int w    = tid >> 6;
    const int lane = tid & 63;
    const int s    = s0 + w;
    const float* qrow = qkv + (size_t)(b * S_ + s) * NW_ + h * DH_;
    qs[w][lane] = qrow[lane];
    __syncthreads();

    const int m = lane & 31;
    const bool hi = lane >= 32;
    double dot = 0.;
    {
        const double* krow = hi ? &k2s[m][0] : &k1s[m][0];
        const float*  qq   = &qs[w][hi ? DHH_ : 0];
#pragma unroll
        for (int d = 0; d < DHH_; ++d)
            dot = fma((double)qq[d], krow[d], dot);
    }

    double val = dot; int idx = m;
#pragma unroll
    for (int t = 0; t < TOPK_; ++t) {
        double bv = val; int bi = idx;
#pragma unroll
        for (int msk = 1; msk <= 16; msk <<= 1) {
            double ov = __shfl_xor(bv, msk);
            int    oi = __shfl_xor(bi, msk);
            if (ov > bv || (ov == bv && oi < bi)) { bv = ov; bi = oi; }
        }
        if (lane == t)      { abuf[w][t] = bv; i1buf[w][t] = bi; }
        if (lane == 32 + t) { bbuf[w][t] = bv; i2buf[w][t] = bi; }
        if (idx == bi) val = -__builtin_huge_val();
    }
    __syncthreads();

    double cval = abuf[w][lane >> 3] + bbuf[w][lane & 7];
    double sv[TOPK_]; int sel[TOPK_];
    double val2 = cval; int idx2 = lane;
#pragma unroll
    for (int t = 0; t < TOPK_; ++t) {
        double bv = val2; int bi = idx2;
#pragma unroll
        for (int msk = 1; msk <= 32; msk <<= 1) {
            double ov = __shfl_xor(bv, msk);
            int    oi = __shfl_xor(bi, msk);
            if (ov > bv || (ov == bv && oi < bi)) { bv = ov; bi = oi; }
        }
        sv[t] = bv; sel[t] = bi;
        if (idx2 == bi) val2 = -__builtin_huge_val();
    }

    double wex[TOPK_]; double wsum = 0.;
#pragma unroll
    for (int t = 0; t < TOPK_; ++t) {
        wex[t] = exp((sv[t] - sv[0]) * 0.125);
        wsum += wex[t];
    }
    const double inv = 1.0 / wsum;
    double o = 0.;
#pragma unroll
    for (int t = 0; t < TOPK_; ++t) {
        int row = i1buf[w][sel[t] >> 3];
        int col = i2buf[w][sel[t] & 7];
        float vvv = qkv[(size_t)(b * S_ + row * M_ + col) * NW_ +
                        VOFF_ + kv * DH_ + lane];
        o = fma(wex[t] * inv, (double)vvv, o);
    }
    aout[(size_t)(b * S_ + s) * (QH_ * DH_) + h * DH_ + lane] = (float)o;
}

// ---------------------------------------------------------------------------
extern "C" void kernel_launch(void* const* d_in, const int* in_sizes, int n_in,
                              void* d_out, int out_size, void* d_ws,
                              size_t ws_size, hipStream_t stream)
{
    const float* x  = (const float*)d_in[0];
    const float* wq = (const float*)d_in[1];
    const float* wk = (const float*)d_in[2];
    const float* wv = (const float*)d_in[3];
    const float* wo = (const float*)d_in[4];
    float* out = (float*)d_out;

    // workspace layout: qkv f32 | k1 f64 | k2 f64 | attn_out f32  (~21 MB)
    float*  wsf  = (float*)d_ws;
    float*  qkv  = wsf;                                  // 2048*1536 f32
    double* k1   = (double*)(qkv + (size_t)BS_ * NW_);   // 8192 f64
    double* k2   = k1 + B_ * KVH_ * M_ * DHH_;           // 8192 f64
    float*  aout = (float*)(k2 + B_ * KVH_ * M_ * DHH_); // 2048*1024 f32

    // 1) fused qkv GEMM, 3-way split bf16 MFMA (score-grade: noise ~3e-6)
    dim3 g1(BS_ / 128, NW_ / 128);
    gemm_mfma_kernel<3, 2><<<g1, 256, 0, stream>>>(
        x, wq, wk, wv, KOFF_, VOFF_, qkv, NW_, DM_);
    // 2) RoPE on q,k (numpy-f32 bit-matched)
    rope_kernel<<<(BS_ * (QH_ + KVH_) * DHH_) / 256, 256, 0, stream>>>(qkv);
    // 3) k1/k2 grid sums (f64)
    k1k2_kernel<<<B_ * KVH_, 256, 0, stream>>>(qkv, k1, k2);
    // 4) two-stage top-k select + 8-key attention (f64 score path)
    select_kernel<<<B_ * QH_ * S_ / 4, 256, 0, stream>>>(qkv, k1, k2, aout);
    // 5) output GEMM, 2-way split bf16 MFMA (value-grade: noise ~2e-5)
    dim3 g2(BS_ / 128, DM_ / 128);
    gemm_mfma_kernel<2, 2><<<g2, 256, 0, stream>>>(
        aout, wo, wo, wo, 1 << 30, 1 << 30, out, DM_, DM_);
}

// Round 5
// 219.197 us; speedup vs baseline: 2.6237x; 1.1886x over previous
//
#include <hip/hip_runtime.h>
#include <hip/hip_bf16.h>
#include <math.h>

// Problem constants (B=2, S=1024, DM=1024, QH=16, KVH=4)
constexpr int B_   = 2;
constexpr int S_   = 1024;
constexpr int DM_  = 1024;
constexpr int QH_  = 16;
constexpr int KVH_ = 4;
constexpr int DH_  = 64;
constexpr int DHH_ = 32;
constexpr int M_   = 32;    // sqrt(S)
constexpr int TOPK_ = 8;
constexpr int BS_  = B_ * S_;                    // 2048
constexpr int NW_  = QH_*DH_ + 2*KVH_*DH_;       // 1536 (q|k|v fused row)
constexpr int KOFF_ = QH_*DH_;                   // 1024
constexpr int VOFF_ = KOFF_ + KVH_*DH_;          // 1280

typedef __attribute__((ext_vector_type(8))) short short8v;   // 8 bf16 (4 VGPR)
typedef __attribute__((ext_vector_type(4))) short short4v;   // 4 bf16 (8B)
typedef __attribute__((ext_vector_type(4))) float float4v;   // MFMA acc

__device__ inline unsigned short bf16_rne(float f) {
    unsigned u = __float_as_uint(f);
    return (unsigned short)((u + 0x7FFFu + ((u >> 16) & 1u)) >> 16);
}
__device__ inline float bf16_back(unsigned short h) {
    return __uint_as_float(((unsigned)h) << 16);
}

// ---------------------------------------------------------------------------
// Split-bf16 MFMA GEMM (unchanged from round 4): C = A @ W^T, K=1024.
// LEVELS=3/CROSS=2 -> score-grade (~3e-6); LEVELS=2/CROSS=2 -> value-grade.
// Tile 128x128, 4 waves (2x2), BK=32, register-staged splits into
// XOR-swizzled LDS, next-chunk global prefetch overlapped with MFMA phase.
// ---------------------------------------------------------------------------
template<int LEVELS, int CROSS>
__global__ __launch_bounds__(256) void gemm_mfma_kernel(
    const float* __restrict__ A,
    const float* __restrict__ W0, const float* __restrict__ W1,
    const float* __restrict__ W2, int n1, int n2,
    float* __restrict__ C, int N, int K)
{
    __shared__ short As[LEVELS * 128 * 32];
    __shared__ short Bs[LEVELS * 128 * 32];
    const int tid = threadIdx.x;
    const int rowBase = blockIdx.x * 128;
    const int colBase = blockIdx.y * 128;
    const int lane = tid & 63, wv = tid >> 6;
    const int wr = wv >> 1, wc = wv & 1;       // wave tile origin /64
    const int fr = lane & 15, fk = lane >> 4;  // fragment row, k-group

    const float* aptr[4]; const float* bptr[4];
    int arow_[4], ac4_[4];
#pragma unroll
    for (int i = 0; i < 4; ++i) {
        int q = i * 256 + tid;
        int row = q >> 3, c4 = q & 7;
        arow_[i] = row; ac4_[i] = c4;
        aptr[i] = A + (size_t)(rowBase + row) * K + c4 * 4;
        int n = colBase + row;
        const float* wrow = (n < n1) ? W0 + (size_t)n * K
                          : (n < n2) ? W1 + (size_t)(n - n1) * K
                                     : W2 + (size_t)(n - n2) * K;
        bptr[i] = wrow + c4 * 4;
    }

    float4 pa[4], pb[4];
#pragma unroll
    for (int i = 0; i < 4; ++i) {
        pa[i] = *reinterpret_cast<const float4*>(aptr[i]);
        pb[i] = *reinterpret_cast<const float4*>(bptr[i]);
    }

    float4v acc[4][4];
#pragma unroll
    for (int mi = 0; mi < 4; ++mi)
#pragma unroll
        for (int ni = 0; ni < 4; ++ni) acc[mi][ni] = (float4v)0.f;

    const int NKC = K >> 5;
    for (int kc = 0; kc < NKC; ++kc) {
#pragma unroll
        for (int i = 0; i < 4; ++i) {
            int row = arow_[i];
            int base = row * 64 + ((ac4_[i] * 8) ^ ((row & 3) << 4));
            float fa[4] = {pa[i].x, pa[i].y, pa[i].z, pa[i].w};
            float fb[4] = {pb[i].x, pb[i].y, pb[i].z, pb[i].w};
#pragma unroll
            for (int l = 0; l < LEVELS; ++l) {
                short4v sa, sb;
#pragma unroll
                for (int e = 0; e < 4; ++e) {
                    unsigned short ha = bf16_rne(fa[e]);
                    unsigned short hb = bf16_rne(fb[e]);
                    sa[e] = (short)ha; sb[e] = (short)hb;
                    fa[e] -= bf16_back(ha);
                    fb[e] -= bf16_back(hb);
                }
                *reinterpret_cast<short4v*>((char*)As + l * 8192 + base) = sa;
                *reinterpret_cast<short4v*>((char*)Bs + l * 8192 + base) = sb;
            }
        }
        __syncthreads();
        if (kc + 1 < NKC) {
#pragma unroll
            for (int i = 0; i < 4; ++i) {
                pa[i] = *reinterpret_cast<const float4*>(aptr[i] + (kc+1)*32);
                pb[i] = *reinterpret_cast<const float4*>(bptr[i] + (kc+1)*32);
            }
        }
        short8v aF[LEVELS][4];
#pragma unroll
        for (int l = 0; l < LEVELS; ++l)
#pragma unroll
            for (int mi = 0; mi < 4; ++mi) {
                int row = wr * 64 + mi * 16 + fr;
                int byte = l * 8192 + row * 64 + ((fk * 16) ^ ((row & 3) << 4));
                aF[l][mi] = *reinterpret_cast<const short8v*>((const char*)As + byte);
            }
#pragma unroll
        for (int lb = 0; lb < LEVELS; ++lb) {
            short8v bF[4];
#pragma unroll
            for (int ni = 0; ni < 4; ++ni) {
                int row = wc * 64 + ni * 16 + fr;
                int byte = lb * 8192 + row * 64 + ((fk * 16) ^ ((row & 3) << 4));
                bF[ni] = *reinterpret_cast<const short8v*>((const char*)Bs + byte);
            }
#pragma unroll
            for (int la = 0; la < LEVELS; ++la) {
                if (la + lb > CROSS) continue;
#pragma unroll
                for (int mi = 0; mi < 4; ++mi)
#pragma unroll
                    for (int ni = 0; ni < 4; ++ni)
                        acc[mi][ni] = __builtin_amdgcn_mfma_f32_16x16x32_bf16(
                            aF[la][mi], bF[ni], acc[mi][ni], 0, 0, 0);
            }
        }
        __syncthreads();
    }
#pragma unroll
    for (int mi = 0; mi < 4; ++mi)
#pragma unroll
        for (int ni = 0; ni < 4; ++ni) {
            int row0 = rowBase + wr * 64 + mi * 16 + fk * 4;
            int col  = colBase + wc * 64 + ni * 16 + fr;
#pragma unroll
            for (int j = 0; j < 4; ++j)
                C[(size_t)(row0 + j) * N + col] = acc[mi][ni][j];
        }
}

// ---------------------------------------------------------------------------
// RoPE in-place, bit-matching the numpy f32 reference (inv_freq with numpy's
// TWO f32 roundings; f32 angle; f64 trig; strict-f32 non-FMA rotation).
// ---------------------------------------------------------------------------
__global__ __launch_bounds__(256) void rope_kernel(float* __restrict__ qkv)
{
    int id = blockIdx.x * 256 + threadIdx.x;   // BS * 20 * 32 threads
    int d  = id & 31;
    int r  = id >> 5;
    int h  = r % (QH_ + KVH_);
    int bs = r / (QH_ + KVH_);
    int s  = bs & (S_ - 1);
    float* base = qkv + (size_t)bs * NW_ +
                  (h < QH_ ? h * DH_ : KOFF_ + (h - QH_) * DH_);
    double e = (double)d * (1.0 / 32.0);
    float pf = (float)pow(10000.0, e);         // == correctly-rounded powf
    float inv_freq = __fdiv_rn(1.0f, pf);      // numpy's 2nd f32 rounding
    float ang = __fmul_rn((float)s, inv_freq);
    double sn64, cs64;
    sincos((double)ang, &sn64, &cs64);
    float cs = (float)cs64;
    float sn = (float)sn64;
    float x1 = base[d];
    float x2 = base[d + DHH_];
    base[d]        = __fadd_rn(__fmul_rn(x1, cs), __fmul_rn(-x2, sn));
    base[d + DHH_] = __fadd_rn(__fmul_rn(x2, cs), __fmul_rn(x1, sn));
}

// ---------------------------------------------------------------------------
// k1/k2 grid sums: f64 internal accumulation, f32 store (select path is f32).
// ---------------------------------------------------------------------------
__global__ __launch_bounds__(256) void k1k2_kernel(
    const float* __restrict__ qkv, float* __restrict__ k1,
    float* __restrict__ k2)
{
    int blk = blockIdx.x;            // b*KVH + kv  (8 blocks)
    int b = blk >> 2, kv = blk & 3;
    int tid = threadIdx.x;
    int d = tid & 31;
    const float* kbase = qkv + (size_t)b * S_ * NW_ + KOFF_ + kv * DH_;
    for (int m = tid >> 5; m < M_; m += 8) {
        double s1 = 0., s2 = 0.;
        for (int mc = 0; mc < M_; ++mc) {
            s1 += (double)kbase[(size_t)(m * M_ + mc) * NW_ + d];
            s2 += (double)kbase[(size_t)(mc * M_ + m) * NW_ + DHH_ + d];
        }
        k1[((b * KVH_ + kv) * M_ + m) * DHH_ + d] = (float)s1;
        k2[((b * KVH_ + kv) * M_ + m) * DHH_ + d] = (float)s2;
    }
}

// ---------------------------------------------------------------------------
// Select + attention, f32 throughout. Identical top-k structure to the
// verified round-3 kernel; dtype change only. Justification: rounds 1<->2
// showed bit-identical output when score noise went 2e-5 -> 1e-9, so f32
// noise (~1e-5) provably causes no selection flips on this input set.
// f64 was costing 2x on FMA/cmp rates and 2x on shuffle count.
// ---------------------------------------------------------------------------
__global__ __launch_bounds__(256) void select_kernel(
    const float* __restrict__ qkv,
    const float* __restrict__ k1g, const float* __restrict__ k2g,
    float* __restrict__ aout)
{
    __shared__ float k1s[M_][DHH_ + 1];   // +1 pad: conflict-free row reads
    __shared__ float k2s[M_][DHH_ + 1];
    __shared__ float qs[4][DH_];
    __shared__ float abuf[4][TOPK_], bbuf[4][TOPK_];
    __shared__ int   i1buf[4][TOPK_], i2buf[4][TOPK_];

    const int tid = threadIdx.x;
    const int bh  = blockIdx.x >> 8;           // S/4 = 256 blocks per (b,h)
    const int s0  = (blockIdx.x & 255) << 2;
    const int b   = bh >> 4;
    const int h   = bh & 15;
    const int kv  = h >> 2;                    // n_rep = 4

    const int kbase = (b * KVH_ + kv) * M_ * DHH_;
    for (int i = tid; i < M_ * DHH_; i += 256) {
        k1s[i >> 5][i & 31] = k1g[kbase + i];
        k2s[i >> 5][i & 31] = k2g[kbase + i];
    }

    const int w    = tid >> 6;
    const int lane = tid & 63;
    const int s    = s0 + w;
    const float* qrow = qkv + (size_t)(b * S_ + s) * NW_ + h * DH_;
    qs[w][lane] = qrow[lane];
    __syncthreads();

    // ---- stage-1 dots (f32)
    const int m = lane & 31;
    const bool hi = lane >= 32;
    float dot = 0.f;
    {
        const float* krow = hi ? &k2s[m][0] : &k1s[m][0];
        const float* qq   = &qs[w][hi ? DHH_ : 0];
#pragma unroll
        for (int d = 0; d < DHH_; ++d)
            dot = fmaf(qq[d], krow[d], dot);
    }

    // ---- top-8 within each 32-lane half (value desc, index asc on ties)
    float val = dot; int idx = m;
#pragma unroll
    for (int t = 0; t < TOPK_; ++t) {
        float bv = val; int bi = idx;
#pragma unroll
        for (int msk = 1; msk <= 16; msk <<= 1) {
            float ov = __shfl_xor(bv, msk);
            int   oi = __shfl_xor(bi, msk);
            if (ov > bv || (ov == bv && oi < bi)) { bv = ov; bi = oi; }
        }
        if (lane == t)      { abuf[w][t] = bv; i1buf[w][t] = bi; }
        if (lane == 32 + t) { bbuf[w][t] = bv; i2buf[w][t] = bi; }
        if (idx == bi) val = -__builtin_huge_valf();
    }
    __syncthreads();

    // ---- stage-2: 64 combined scores, full-wave top-8
    float cval = abuf[w][lane >> 3] + bbuf[w][lane & 7];
    float sv[TOPK_]; int sel[TOPK_];
    float val2 = cval; int idx2 = lane;
#pragma unroll
    for (int t = 0; t < TOPK_; ++t) {
        float bv = val2; int bi = idx2;
#pragma unroll
        for (int msk = 1; msk <= 32; msk <<= 1) {
            float ov = __shfl_xor(bv, msk);
            int   oi = __shfl_xor(bi, msk);
            if (ov > bv || (ov == bv && oi < bi)) { bv = ov; bi = oi; }
        }
        sv[t] = bv; sel[t] = bi;
        if (idx2 == bi) val2 = -__builtin_huge_valf();
    }

    // ---- softmax over 8 (scores/8, max-subtracted) + weighted v gather
    float wex[TOPK_]; float wsum = 0.f;
#pragma unroll
    for (int t = 0; t < TOPK_; ++t) {
        wex[t] = expf((sv[t] - sv[0]) * 0.125f);
        wsum += wex[t];
    }
    const float inv = 1.0f / wsum;
    float o = 0.f;
#pragma unroll
    for (int t = 0; t < TOPK_; ++t) {
        int row = i1buf[w][sel[t] >> 3];
        int col = i2buf[w][sel[t] & 7];
        float vvv = qkv[(size_t)(b * S_ + row * M_ + col) * NW_ +
                        VOFF_ + kv * DH_ + lane];
        o = fmaf(wex[t] * inv, vvv, o);
    }
    aout[(size_t)(b * S_ + s) * (QH_ * DH_) + h * DH_ + lane] = o;
}

// ---------------------------------------------------------------------------
extern "C" void kernel_launch(void* const* d_in, const int* in_sizes, int n_in,
                              void* d_out, int out_size, void* d_ws,
                              size_t ws_size, hipStream_t stream)
{
    const float* x  = (const float*)d_in[0];
    const float* wq = (const float*)d_in[1];
    const float* wk = (const float*)d_in[2];
    const float* wv = (const float*)d_in[3];
    const float* wo = (const float*)d_in[4];
    float* out = (float*)d_out;

    // workspace layout: qkv f32 | k1 f32 | k2 f32 | attn_out f32  (~21 MB)
    float* wsf  = (float*)d_ws;
    float* qkv  = wsf;                                   // 2048*1536 f32
    float* k1   = qkv + (size_t)BS_ * NW_;               // 8192 f32
    float* k2   = k1 + B_ * KVH_ * M_ * DHH_;            // 8192 f32
    float* aout = k2 + B_ * KVH_ * M_ * DHH_;            // 2048*1024 f32

    // 1) fused qkv GEMM, 3-way split bf16 MFMA (score-grade: noise ~3e-6)
    dim3 g1(BS_ / 128, NW_ / 128);
    gemm_mfma_kernel<3, 2><<<g1, 256, 0, stream>>>(
        x, wq, wk, wv, KOFF_, VOFF_, qkv, NW_, DM_);
    // 2) RoPE on q,k (numpy-f32 bit-matched)
    rope_kernel<<<(BS_ * (QH_ + KVH_) * DHH_) / 256, 256, 0, stream>>>(qkv);
    // 3) k1/k2 grid sums (f64 accum, f32 store)
    k1k2_kernel<<<B_ * KVH_, 256, 0, stream>>>(qkv, k1, k2);
    // 4) two-stage top-k select + 8-key attention (f32)
    select_kernel<<<B_ * QH_ * S_ / 4, 256, 0, stream>>>(qkv, k1, k2, aout);
    // 5) output GEMM, 2-way split bf16 MFMA (value-grade: noise ~2e-5)
    dim3 g2(BS_ / 128, DM_ / 128);
    gemm_mfma_kernel<2, 2><<<g2, 256, 0, stream>>>(
        aout, wo, wo, wo, 1 << 30, 1 << 30, out, DM_, DM_);
}

// Round 6
// 188.089 us; speedup vs baseline: 3.0576x; 1.1654x over previous
//
#include <hip/hip_runtime.h>
#include <hip/hip_bf16.h>
#include <math.h>

// Problem constants (B=2, S=1024, DM=1024, QH=16, KVH=4)
constexpr int B_   = 2;
constexpr int S_   = 1024;
constexpr int DM_  = 1024;
constexpr int QH_  = 16;
constexpr int KVH_ = 4;
constexpr int DH_  = 64;
constexpr int DHH_ = 32;
constexpr int M_   = 32;    // sqrt(S)
constexpr int TOPK_ = 8;
constexpr int BS_  = B_ * S_;                    // 2048
constexpr int NW_  = QH_*DH_ + 2*KVH_*DH_;       // 1536 (q|k|v fused row)
constexpr int KOFF_ = QH_*DH_;                   // 1024
constexpr int VOFF_ = KOFF_ + KVH_*DH_;          // 1280

typedef __attribute__((ext_vector_type(8))) short short8v;   // 8 bf16 (4 VGPR)
typedef __attribute__((ext_vector_type(4))) short short4v;   // 4 bf16 (8B)
typedef __attribute__((ext_vector_type(4))) float float4v;   // MFMA acc

__device__ inline unsigned short bf16_rne(float f) {
    unsigned u = __float_as_uint(f);
    return (unsigned short)((u + 0x7FFFu + ((u >> 16) & 1u)) >> 16);
}
__device__ inline float bf16_back(unsigned short h) {
    return __uint_as_float(((unsigned)h) << 16);
}

// ---------------------------------------------------------------------------
// Split-bf16 MFMA GEMM (unchanged from round 4): C = A @ W^T, K=1024.
// LEVELS=3/CROSS=2 -> score-grade (~3e-6); LEVELS=2/CROSS=2 -> value-grade.
// Tile 128x128, 4 waves (2x2), BK=32, register-staged splits into
// XOR-swizzled LDS, next-chunk global prefetch overlapped with MFMA phase.
// ---------------------------------------------------------------------------
template<int LEVELS, int CROSS>
__global__ __launch_bounds__(256) void gemm_mfma_kernel(
    const float* __restrict__ A,
    const float* __restrict__ W0, const float* __restrict__ W1,
    const float* __restrict__ W2, int n1, int n2,
    float* __restrict__ C, int N, int K)
{
    __shared__ short As[LEVELS * 128 * 32];
    __shared__ short Bs[LEVELS * 128 * 32];
    const int tid = threadIdx.x;
    const int rowBase = blockIdx.x * 128;
    const int colBase = blockIdx.y * 128;
    const int lane = tid & 63, wv = tid >> 6;
    const int wr = wv >> 1, wc = wv & 1;       // wave tile origin /64
    const int fr = lane & 15, fk = lane >> 4;  // fragment row, k-group

    const float* aptr[4]; const float* bptr[4];
    int arow_[4], ac4_[4];
#pragma unroll
    for (int i = 0; i < 4; ++i) {
        int q = i * 256 + tid;
        int row = q >> 3, c4 = q & 7;
        arow_[i] = row; ac4_[i] = c4;
        aptr[i] = A + (size_t)(rowBase + row) * K + c4 * 4;
        int n = colBase + row;
        const float* wrow = (n < n1) ? W0 + (size_t)n * K
                          : (n < n2) ? W1 + (size_t)(n - n1) * K
                                     : W2 + (size_t)(n - n2) * K;
        bptr[i] = wrow + c4 * 4;
    }

    float4 pa[4], pb[4];
#pragma unroll
    for (int i = 0; i < 4; ++i) {
        pa[i] = *reinterpret_cast<const float4*>(aptr[i]);
        pb[i] = *reinterpret_cast<const float4*>(bptr[i]);
    }

    float4v acc[4][4];
#pragma unroll
    for (int mi = 0; mi < 4; ++mi)
#pragma unroll
        for (int ni = 0; ni < 4; ++ni) acc[mi][ni] = (float4v)0.f;

    const int NKC = K >> 5;
    for (int kc = 0; kc < NKC; ++kc) {
#pragma unroll
        for (int i = 0; i < 4; ++i) {
            int row = arow_[i];
            int base = row * 64 + ((ac4_[i] * 8) ^ ((row & 3) << 4));
            float fa[4] = {pa[i].x, pa[i].y, pa[i].z, pa[i].w};
            float fb[4] = {pb[i].x, pb[i].y, pb[i].z, pb[i].w};
#pragma unroll
            for (int l = 0; l < LEVELS; ++l) {
                short4v sa, sb;
#pragma unroll
                for (int e = 0; e < 4; ++e) {
                    unsigned short ha = bf16_rne(fa[e]);
                    unsigned short hb = bf16_rne(fb[e]);
                    sa[e] = (short)ha; sb[e] = (short)hb;
                    fa[e] -= bf16_back(ha);
                    fb[e] -= bf16_back(hb);
                }
                *reinterpret_cast<short4v*>((char*)As + l * 8192 + base) = sa;
                *reinterpret_cast<short4v*>((char*)Bs + l * 8192 + base) = sb;
            }
        }
        __syncthreads();
        if (kc + 1 < NKC) {
#pragma unroll
            for (int i = 0; i < 4; ++i) {
                pa[i] = *reinterpret_cast<const float4*>(aptr[i] + (kc+1)*32);
                pb[i] = *reinterpret_cast<const float4*>(bptr[i] + (kc+1)*32);
            }
        }
        short8v aF[LEVELS][4];
#pragma unroll
        for (int l = 0; l < LEVELS; ++l)
#pragma unroll
            for (int mi = 0; mi < 4; ++mi) {
                int row = wr * 64 + mi * 16 + fr;
                int byte = l * 8192 + row * 64 + ((fk * 16) ^ ((row & 3) << 4));
                aF[l][mi] = *reinterpret_cast<const short8v*>((const char*)As + byte);
            }
#pragma unroll
        for (int lb = 0; lb < LEVELS; ++lb) {
            short8v bF[4];
#pragma unroll
            for (int ni = 0; ni < 4; ++ni) {
                int row = wc * 64 + ni * 16 + fr;
                int byte = lb * 8192 + row * 64 + ((fk * 16) ^ ((row & 3) << 4));
                bF[ni] = *reinterpret_cast<const short8v*>((const char*)Bs + byte);
            }
#pragma unroll
            for (int la = 0; la < LEVELS; ++la) {
                if (la + lb > CROSS) continue;
#pragma unroll
                for (int mi = 0; mi < 4; ++mi)
#pragma unroll
                    for (int ni = 0; ni < 4; ++ni)
                        acc[mi][ni] = __builtin_amdgcn_mfma_f32_16x16x32_bf16(
                            aF[la][mi], bF[ni], acc[mi][ni], 0, 0, 0);
            }
        }
        __syncthreads();
    }
#pragma unroll
    for (int mi = 0; mi < 4; ++mi)
#pragma unroll
        for (int ni = 0; ni < 4; ++ni) {
            int row0 = rowBase + wr * 64 + mi * 16 + fk * 4;
            int col  = colBase + wc * 64 + ni * 16 + fr;
#pragma unroll
            for (int j = 0; j < 4; ++j)
                C[(size_t)(row0 + j) * N + col] = acc[mi][ni][j];
        }
}

// ---------------------------------------------------------------------------
// RoPE in-place, bit-matching the numpy f32 reference (inv_freq with numpy's
// TWO f32 roundings; f32 angle; f64 trig; strict-f32 non-FMA rotation).
// ---------------------------------------------------------------------------
__global__ __launch_bounds__(256) void rope_kernel(float* __restrict__ qkv)
{
    int id = blockIdx.x * 256 + threadIdx.x;   // BS * 20 * 32 threads
    int d  = id & 31;
    int r  = id >> 5;
    int h  = r % (QH_ + KVH_);
    int bs = r / (QH_ + KVH_);
    int s  = bs & (S_ - 1);
    float* base = qkv + (size_t)bs * NW_ +
                  (h < QH_ ? h * DH_ : KOFF_ + (h - QH_) * DH_);
    double e = (double)d * (1.0 / 32.0);
    float pf = (float)pow(10000.0, e);         // == correctly-rounded powf
    float inv_freq = __fdiv_rn(1.0f, pf);      // numpy's 2nd f32 rounding
    float ang = __fmul_rn((float)s, inv_freq);
    double sn64, cs64;
    sincos((double)ang, &sn64, &cs64);
    float cs = (float)cs64;
    float sn = (float)sn64;
    float x1 = base[d];
    float x2 = base[d + DHH_];
    base[d]        = __fadd_rn(__fmul_rn(x1, cs), __fmul_rn(-x2, sn));
    base[d + DHH_] = __fadd_rn(__fmul_rn(x2, cs), __fmul_rn(x1, sn));
}

// ---------------------------------------------------------------------------
// k1/k2 grid sums: f64 internal accumulation, f32 store (select path is f32).
// ---------------------------------------------------------------------------
__global__ __launch_bounds__(256) void k1k2_kernel(
    const float* __restrict__ qkv, float* __restrict__ k1,
    float* __restrict__ k2)
{
    int blk = blockIdx.x;            // b*KVH + kv  (8 blocks)
    int b = blk >> 2, kv = blk & 3;
    int tid = threadIdx.x;
    int d = tid & 31;
    const float* kbase = qkv + (size_t)b * S_ * NW_ + KOFF_ + kv * DH_;
    for (int m = tid >> 5; m < M_; m += 8) {
        double s1 = 0., s2 = 0.;
        for (int mc = 0; mc < M_; ++mc) {
            s1 += (double)kbase[(size_t)(m * M_ + mc) * NW_ + d];
            s2 += (double)kbase[(size_t)(mc * M_ + m) * NW_ + DHH_ + d];
        }
        k1[((b * KVH_ + kv) * M_ + m) * DHH_ + d] = (float)s1;
        k2[((b * KVH_ + kv) * M_ + m) * DHH_ + d] = (float)s2;
    }
}

// ---------------------------------------------------------------------------
// Select + attention, bitonic-sort selection (replaces iterative extraction:
// 88 -> 36 sequential compare-exchange steps; rocprof showed the old kernel
// issue-bound at VALUBusy 68% on these chains).
// Stage 1: each 32-lane half sorts (dot, m) by (value desc, index asc) ==
// jax top_k order; lanes 0-7 / 32-39 hold (a,idx1) / (b,idx2).
// Stage 2: cand value a[c>>3]+b[c&7] (exact algebraic identity with q.cand),
// 64-lane bitonic sort by (value desc, cand asc) == top-8 of 64 with jax tie
// semantics. Softmax on lanes 0-7, broadcast-gather of 8 v rows. No LDS for
// selection state, one barrier total.
// ---------------------------------------------------------------------------
__global__ __launch_bounds__(256) void select_kernel(
    const float* __restrict__ qkv,
    const float* __restrict__ k1g, const float* __restrict__ k2g,
    float* __restrict__ aout)
{
    __shared__ float k1s[M_][DHH_ + 1];   // +1 pad: conflict-free row reads
    __shared__ float k2s[M_][DHH_ + 1];
    __shared__ float qs[4][DH_];

    const int tid = threadIdx.x;
    const int bh  = blockIdx.x >> 8;           // S/4 = 256 blocks per (b,h)
    const int s0  = (blockIdx.x & 255) << 2;
    const int b   = bh >> 4;
    const int h   = bh & 15;
    const int kv  = h >> 2;                    // n_rep = 4

    const int kbase = (b * KVH_ + kv) * M_ * DHH_;
    for (int i = tid; i < M_ * DHH_; i += 256) {
        k1s[i >> 5][i & 31] = k1g[kbase + i];
        k2s[i >> 5][i & 31] = k2g[kbase + i];
    }

    const int w    = tid >> 6;
    const int lane = tid & 63;
    const int s    = s0 + w;
    const float* qrow = qkv + (size_t)(b * S_ + s) * NW_ + h * DH_;
    qs[w][lane] = qrow[lane];
    __syncthreads();

    // ---- stage-1 dots (f32): lanes 0-31 -> s1[m], lanes 32-63 -> s2[m]
    const int m = lane & 31;
    const bool hi = lane >= 32;
    float v1 = 0.f;
    {
        const float* krow = hi ? &k2s[m][0] : &k1s[m][0];
        const float* qq   = &qs[w][hi ? DHH_ : 0];
#pragma unroll
        for (int d = 0; d < DHH_; ++d) v1 = fmaf(qq[d], krow[d], v1);
    }
    int i1 = m;

    // ---- bitonic sort desc within each 32-half, key (v desc, idx asc)
    const int l5 = lane & 31;
#pragma unroll
    for (int k = 2; k <= 32; k <<= 1) {
#pragma unroll
        for (int j = k >> 1; j > 0; j >>= 1) {
            float ov = __shfl_xor(v1, j);
            int   oi = __shfl_xor(i1, j);
            bool gt    = (v1 > ov) || (v1 == ov && i1 < oi);
            bool dirD  = ((l5 & k) == 0);
            bool lower = ((lane & j) == 0);
            if (gt != (dirD == lower)) { v1 = ov; i1 = oi; }
        }
    }
    // lanes 0-7: rank-t of s1 (a, idx1); lanes 32-39: rank-t of s2 (b, idx2)

    // ---- stage-2: 64 candidates c = i*8+j, value a[i]+b[j]
    float av = __shfl(v1, lane >> 3);
    float bv = __shfl(v1, 32 + (lane & 7));
    float v2 = av + bv;
    int   c2 = lane;
#pragma unroll
    for (int k = 2; k <= 64; k <<= 1) {
#pragma unroll
        for (int j = k >> 1; j > 0; j >>= 1) {
            float ov = __shfl_xor(v2, j);
            int   oc = __shfl_xor(c2, j);
            bool gt    = (v2 > ov) || (v2 == ov && c2 < oc);
            bool dirD  = ((lane & k) == 0);
            bool lower = ((lane & j) == 0);
            if (gt != (dirD == lower)) { v2 = ov; c2 = oc; }
        }
    }
    // lane t in 0..7 holds rank-t (v2, c2)

    // ---- softmax over 8 (scores/8, max-subtracted) on lanes 0-7
    float vmax = __shfl(v2, 0);
    float e = (lane < 8) ? expf((v2 - vmax) * 0.125f) : 0.f;
    float sum = e;
#pragma unroll
    for (int msk = 1; msk <= 4; msk <<= 1) sum += __shfl_xor(sum, msk);
    float wn = e / sum;                        // valid on lanes 0-7

    // ---- weighted gather of 8 v rows (row/col broadcast per term)
    const float* vbase = qkv + (size_t)b * S_ * NW_ + VOFF_ + kv * DH_ + lane;
    float o = 0.f;
#pragma unroll
    for (int t = 0; t < TOPK_; ++t) {
        float wt  = __shfl(wn, t);
        int   ct  = __shfl(c2, t);
        int   row = __shfl(i1, ct >> 3);
        int   col = __shfl(i1, 32 + (ct & 7));
        o = fmaf(wt, vbase[(size_t)(row * M_ + col) * NW_], o);
    }
    aout[(size_t)(b * S_ + s) * (QH_ * DH_) + h * DH_ + lane] = o;
}

// ---------------------------------------------------------------------------
extern "C" void kernel_launch(void* const* d_in, const int* in_sizes, int n_in,
                              void* d_out, int out_size, void* d_ws,
                              size_t ws_size, hipStream_t stream)
{
    const float* x  = (const float*)d_in[0];
    const float* wq = (const float*)d_in[1];
    const float* wk = (const float*)d_in[2];
    const float* wv = (const float*)d_in[3];
    const float* wo = (const float*)d_in[4];
    float* out = (float*)d_out;

    // workspace layout: qkv f32 | k1 f32 | k2 f32 | attn_out f32  (~21 MB)
    float* wsf  = (float*)d_ws;
    float* qkv  = wsf;                                   // 2048*1536 f32
    float* k1   = qkv + (size_t)BS_ * NW_;               // 8192 f32
    float* k2   = k1 + B_ * KVH_ * M_ * DHH_;            // 8192 f32
    float* aout = k2 + B_ * KVH_ * M_ * DHH_;            // 2048*1024 f32

    // 1) fused qkv GEMM, 3-way split bf16 MFMA (score-grade: noise ~3e-6)
    dim3 g1(BS_ / 128, NW_ / 128);
    gemm_mfma_kernel<3, 2><<<g1, 256, 0, stream>>>(
        x, wq, wk, wv, KOFF_, VOFF_, qkv, NW_, DM_);
    // 2) RoPE on q,k (numpy-f32 bit-matched)
    rope_kernel<<<(BS_ * (QH_ + KVH_) * DHH_) / 256, 256, 0, stream>>>(qkv);
    // 3) k1/k2 grid sums (f64 accum, f32 store)
    k1k2_kernel<<<B_ * KVH_, 256, 0, stream>>>(qkv, k1, k2);
    // 4) two-stage top-k select + 8-key attention (bitonic, f32)
    select_kernel<<<B_ * QH_ * S_ / 4, 256, 0, stream>>>(qkv, k1, k2, aout);
    // 5) output GEMM, 2-way split bf16 MFMA (value-grade: noise ~2e-5)
    dim3 g2(BS_ / 128, DM_ / 128);
    gemm_mfma_kernel<2, 2><<<g2, 256, 0, stream>>>(
        aout, wo, wo, wo, 1 << 30, 1 << 30, out, DM_, DM_);
}

// Round 8
// 142.377 us; speedup vs baseline: 4.0393x; 1.3211x over previous
//
#include <hip/hip_runtime.h>
#include <hip/hip_bf16.h>
#include <math.h>

// Problem constants (B=2, S=1024, DM=1024, QH=16, KVH=4)
constexpr int B_   = 2;
constexpr int S_   = 1024;
constexpr int DM_  = 1024;
constexpr int QH_  = 16;
constexpr int KVH_ = 4;
constexpr int DH_  = 64;
constexpr int DHH_ = 32;
constexpr int M_   = 32;    // sqrt(S)
constexpr int TOPK_ = 8;
constexpr int BS_  = B_ * S_;                    // 2048
constexpr int NW_  = QH_*DH_ + 2*KVH_*DH_;       // 1536 (q|k|v fused row)
constexpr int KOFF_ = QH_*DH_;                   // 1024
constexpr int VOFF_ = KOFF_ + KVH_*DH_;          // 1280

typedef __attribute__((ext_vector_type(8))) short short8v;   // 8 bf16 (4 VGPR)
typedef __attribute__((ext_vector_type(4))) short short4v;   // 4 bf16 (8B)
typedef __attribute__((ext_vector_type(4))) float float4v;   // MFMA acc

__device__ inline unsigned short bf16_rne(float f) {
    unsigned u = __float_as_uint(f);
    return (unsigned short)((u + 0x7FFFu + ((u >> 16) & 1u)) >> 16);
}
__device__ inline float bf16_back(unsigned short h) {
    return __uint_as_float(((unsigned)h) << 16);
}

// ---------------------------------------------------------------------------
// Split-bf16 MFMA GEMM: C = A @ W^T, K=1024.  64x64 tile, 4 waves (2x2),
// wave tile 32x32 (acc[2][2]), BK=32, 768/512-block grids (~3 blocks/CU;
// fixes round-6's 7.5% occupancy).  Swizzle ((row>>1)&3)<<4: write/read
// XOR pair verified bijective+consistent; fragment reads 2-way (free).
//
// NUMERICS LEDGER (proven-safe score noise is ~1e-6: rounds 1<->2 were
// bit-identical at f32-serial-accum noise ~1e-6).
//   qkv: LEVELS=3/CROSS=2 (6 products) -> split residual 2^-27, score noise
//        ~1e-7.  ROUND-7 POST-MORTEM: LEVELS=2 has representation residual
//        2^-18|x| -> ~4e-6 score noise (CROSS irrelevant: h2g2 is only
//        ~6e-7; the residual needs a THIRD level) -> ~1 top-k flip, 0.042.
//   out: LEVELS=1 plain bf16 -> value noise ~1e-3, max ~5e-3 vs threshold
//        0.0159; cannot flip selections (post-selection).
// ---------------------------------------------------------------------------
template<int LEVELS, int CROSS>
__global__ __launch_bounds__(256) void gemm_mfma_kernel(
    const float* __restrict__ A,
    const float* __restrict__ W0, const float* __restrict__ W1,
    const float* __restrict__ W2, int n1, int n2,
    float* __restrict__ C, int N, int K)
{
    __shared__ short As[LEVELS * 64 * 32];   // 4 KB per level
    __shared__ short Bs[LEVELS * 64 * 32];
    const int tid = threadIdx.x;
    const int rowBase = blockIdx.x * 64;
    const int colBase = blockIdx.y * 64;
    const int lane = tid & 63, wv = tid >> 6;
    const int wr = wv >> 1, wc = wv & 1;       // wave tile origin /32
    const int fr = lane & 15, fk = lane >> 4;  // fragment row, k-group

    // staging: 64x32 floats = 512 float4 per array, 2 per thread
    const float* aptr[2]; const float* bptr[2];
    int arow_[2], ac4_[2];
#pragma unroll
    for (int i = 0; i < 2; ++i) {
        int q = i * 256 + tid;
        int row = q >> 3, c4 = q & 7;
        arow_[i] = row; ac4_[i] = c4;
        aptr[i] = A + (size_t)(rowBase + row) * K + c4 * 4;
        int n = colBase + row;
        const float* wrow = (n < n1) ? W0 + (size_t)n * K
                          : (n < n2) ? W1 + (size_t)(n - n1) * K
                                     : W2 + (size_t)(n - n2) * K;
        bptr[i] = wrow + c4 * 4;
    }

    float4 pa[2], pb[2];
#pragma unroll
    for (int i = 0; i < 2; ++i) {
        pa[i] = *reinterpret_cast<const float4*>(aptr[i]);
        pb[i] = *reinterpret_cast<const float4*>(bptr[i]);
    }

    float4v acc[2][2];
#pragma unroll
    for (int mi = 0; mi < 2; ++mi)
#pragma unroll
        for (int ni = 0; ni < 2; ++ni) acc[mi][ni] = (float4v)0.f;

    const int NKC = K >> 5;
    for (int kc = 0; kc < NKC; ++kc) {
        // ---- split-convert + LDS write
#pragma unroll
        for (int i = 0; i < 2; ++i) {
            int row = arow_[i];
            int base = row * 64 + ((ac4_[i] * 8) ^ (((row >> 1) & 3) << 4));
            float fa[4] = {pa[i].x, pa[i].y, pa[i].z, pa[i].w};
            float fb[4] = {pb[i].x, pb[i].y, pb[i].z, pb[i].w};
#pragma unroll
            for (int l = 0; l < LEVELS; ++l) {
                short4v sa, sb;
#pragma unroll
                for (int e = 0; e < 4; ++e) {
                    unsigned short ha = bf16_rne(fa[e]);
                    unsigned short hb = bf16_rne(fb[e]);
                    sa[e] = (short)ha; sb[e] = (short)hb;
                    fa[e] -= bf16_back(ha);
                    fb[e] -= bf16_back(hb);
                }
                *reinterpret_cast<short4v*>((char*)As + l * 4096 + base) = sa;
                *reinterpret_cast<short4v*>((char*)Bs + l * 4096 + base) = sb;
            }
        }
        __syncthreads();
        // ---- prefetch next chunk (overlaps MFMA phase)
        if (kc + 1 < NKC) {
#pragma unroll
            for (int i = 0; i < 2; ++i) {
                pa[i] = *reinterpret_cast<const float4*>(aptr[i] + (kc+1)*32);
                pb[i] = *reinterpret_cast<const float4*>(bptr[i] + (kc+1)*32);
            }
        }
        // ---- fragment loads + MFMA
        short8v aF[LEVELS][2];
#pragma unroll
        for (int l = 0; l < LEVELS; ++l)
#pragma unroll
            for (int mi = 0; mi < 2; ++mi) {
                int row = wr * 32 + mi * 16 + fr;
                int byte = l * 4096 + row * 64 +
                           ((fk * 16) ^ (((row >> 1) & 3) << 4));
                aF[l][mi] = *reinterpret_cast<const short8v*>((const char*)As + byte);
            }
#pragma unroll
        for (int lb = 0; lb < LEVELS; ++lb) {
            short8v bF[2];
#pragma unroll
            for (int ni = 0; ni < 2; ++ni) {
                int row = wc * 32 + ni * 16 + fr;
                int byte = lb * 4096 + row * 64 +
                           ((fk * 16) ^ (((row >> 1) & 3) << 4));
                bF[ni] = *reinterpret_cast<const short8v*>((const char*)Bs + byte);
            }
#pragma unroll
            for (int la = 0; la < LEVELS; ++la) {
                if (la + lb > CROSS) continue;
#pragma unroll
                for (int mi = 0; mi < 2; ++mi)
#pragma unroll
                    for (int ni = 0; ni < 2; ++ni)
                        acc[mi][ni] = __builtin_amdgcn_mfma_f32_16x16x32_bf16(
                            aF[la][mi], bF[ni], acc[mi][ni], 0, 0, 0);
            }
        }
        __syncthreads();
    }
    // ---- epilogue: C/D layout col=lane&15, row=(lane>>4)*4+j
#pragma unroll
    for (int mi = 0; mi < 2; ++mi)
#pragma unroll
        for (int ni = 0; ni < 2; ++ni) {
            int row0 = rowBase + wr * 32 + mi * 16 + fk * 4;
            int col  = colBase + wc * 32 + ni * 16 + fr;
#pragma unroll
            for (int j = 0; j < 4; ++j)
                C[(size_t)(row0 + j) * N + col] = acc[mi][ni][j];
        }
}

// ---------------------------------------------------------------------------
// RoPE in-place, bit-matching the numpy f32 reference (inv_freq with numpy's
// TWO f32 roundings; f32 angle; f64 trig; strict-f32 non-FMA rotation).
// ---------------------------------------------------------------------------
__global__ __launch_bounds__(256) void rope_kernel(float* __restrict__ qkv)
{
    int id = blockIdx.x * 256 + threadIdx.x;   // BS * 20 * 32 threads
    int d  = id & 31;
    int r  = id >> 5;
    int h  = r % (QH_ + KVH_);
    int bs = r / (QH_ + KVH_);
    int s  = bs & (S_ - 1);
    float* base = qkv + (size_t)bs * NW_ +
                  (h < QH_ ? h * DH_ : KOFF_ + (h - QH_) * DH_);
    double e = (double)d * (1.0 / 32.0);
    float pf = (float)pow(10000.0, e);         // == correctly-rounded powf
    float inv_freq = __fdiv_rn(1.0f, pf);      // numpy's 2nd f32 rounding
    float ang = __fmul_rn((float)s, inv_freq);
    double sn64, cs64;
    sincos((double)ang, &sn64, &cs64);
    float cs = (float)cs64;
    float sn = (float)sn64;
    float x1 = base[d];
    float x2 = base[d + DHH_];
    base[d]        = __fadd_rn(__fmul_rn(x1, cs), __fmul_rn(-x2, sn));
    base[d + DHH_] = __fadd_rn(__fmul_rn(x2, cs), __fmul_rn(x1, sn));
}

// ---------------------------------------------------------------------------
// k1/k2 grid sums: f64 accum, f32 store.  32 blocks.
// ---------------------------------------------------------------------------
__global__ __launch_bounds__(256) void k1k2_kernel(
    const float* __restrict__ qkv, float* __restrict__ k1,
    float* __restrict__ k2)
{
    int blk   = blockIdx.x;          // bkv*4 + chunk  (32 blocks)
    int bkv   = blk >> 2;
    int chunk = blk & 3;
    int b = bkv >> 2, kv = bkv & 3;
    int tid = threadIdx.x;
    int d  = tid & 31;
    int m  = chunk * 8 + (tid >> 5);
    const float* kbase = qkv + (size_t)b * S_ * NW_ + KOFF_ + kv * DH_;
    double s1 = 0., s2 = 0.;
    for (int mc = 0; mc < M_; ++mc) {
        s1 += (double)kbase[(size_t)(m * M_ + mc) * NW_ + d];
        s2 += (double)kbase[(size_t)(mc * M_ + m) * NW_ + DHH_ + d];
    }
    k1[((b * KVH_ + kv) * M_ + m) * DHH_ + d] = (float)s1;
    k2[((b * KVH_ + kv) * M_ + m) * DHH_ + d] = (float)s2;
}

// ---------------------------------------------------------------------------
// Select + attention, bitonic-sort selection (round-6 verified).
// ---------------------------------------------------------------------------
__global__ __launch_bounds__(256) void select_kernel(
    const float* __restrict__ qkv,
    const float* __restrict__ k1g, const float* __restrict__ k2g,
    float* __restrict__ aout)
{
    __shared__ float k1s[M_][DHH_ + 1];   // +1 pad: conflict-free row reads
    __shared__ float k2s[M_][DHH_ + 1];
    __shared__ float qs[4][DH_];

    const int tid = threadIdx.x;
    const int bh  = blockIdx.x >> 8;           // S/4 = 256 blocks per (b,h)
    const int s0  = (blockIdx.x & 255) << 2;
    const int b   = bh >> 4;
    const int h   = bh & 15;
    const int kv  = h >> 2;                    // n_rep = 4

    const int kbase = (b * KVH_ + kv) * M_ * DHH_;
    for (int i = tid; i < M_ * DHH_; i += 256) {
        k1s[i >> 5][i & 31] = k1g[kbase + i];
        k2s[i >> 5][i & 31] = k2g[kbase + i];
    }

    const int w    = tid >> 6;
    const int lane = tid & 63;
    const int s    = s0 + w;
    const float* qrow = qkv + (size_t)(b * S_ + s) * NW_ + h * DH_;
    qs[w][lane] = qrow[lane];
    __syncthreads();

    // ---- stage-1 dots (f32): lanes 0-31 -> s1[m], lanes 32-63 -> s2[m]
    const int m = lane & 31;
    const bool hi = lane >= 32;
    float v1 = 0.f;
    {
        const float* krow = hi ? &k2s[m][0] : &k1s[m][0];
        const float* qq   = &qs[w][hi ? DHH_ : 0];
#pragma unroll
        for (int d = 0; d < DHH_; ++d) v1 = fmaf(qq[d], krow[d], v1);
    }
    int i1 = m;

    // ---- bitonic sort desc within each 32-half, key (v desc, idx asc)
    const int l5 = lane & 31;
#pragma unroll
    for (int k = 2; k <= 32; k <<= 1) {
#pragma unroll
        for (int j = k >> 1; j > 0; j >>= 1) {
            float ov = __shfl_xor(v1, j);
            int   oi = __shfl_xor(i1, j);
            bool gt    = (v1 > ov) || (v1 == ov && i1 < oi);
            bool dirD  = ((l5 & k) == 0);
            bool lower = ((lane & j) == 0);
            if (gt != (dirD == lower)) { v1 = ov; i1 = oi; }
        }
    }
    // lanes 0-7: rank-t of s1 (a, idx1); lanes 32-39: rank-t of s2 (b, idx2)

    // ---- stage-2: 64 candidates c = i*8+j, value a[i]+b[j]
    float av = __shfl(v1, lane >> 3);
    float bv = __shfl(v1, 32 + (lane & 7));
    float v2 = av + bv;
    int   c2 = lane;
#pragma unroll
    for (int k = 2; k <= 64; k <<= 1) {
#pragma unroll
        for (int j = k >> 1; j > 0; j >>= 1) {
            float ov = __shfl_xor(v2, j);
            int   oc = __shfl_xor(c2, j);
            bool gt    = (v2 > ov) || (v2 == ov && c2 < oc);
            bool dirD  = ((lane & k) == 0);
            bool lower = ((lane & j) == 0);
            if (gt != (dirD == lower)) { v2 = ov; c2 = oc; }
        }
    }
    // lane t in 0..7 holds rank-t (v2, c2)

    // ---- softmax over 8 (scores/8, max-subtracted) on lanes 0-7
    float vmax = __shfl(v2, 0);
    float e = (lane < 8) ? expf((v2 - vmax) * 0.125f) : 0.f;
    float sum = e;
#pragma unroll
    for (int msk = 1; msk <= 4; msk <<= 1) sum += __shfl_xor(sum, msk);
    float wn = e / sum;                        // valid on lanes 0-7

    // ---- weighted gather of 8 v rows (row/col broadcast per term)
    const float* vbase = qkv + (size_t)b * S_ * NW_ + VOFF_ + kv * DH_ + lane;
    float o = 0.f;
#pragma unroll
    for (int t = 0; t < TOPK_; ++t) {
        float wt  = __shfl(wn, t);
        int   ct  = __shfl(c2, t);
        int   row = __shfl(i1, ct >> 3);
        int   col = __shfl(i1, 32 + (ct & 7));
        o = fmaf(wt, vbase[(size_t)(row * M_ + col) * NW_], o);
    }
    aout[(size_t)(b * S_ + s) * (QH_ * DH_) + h * DH_ + lane] = o;
}

// ---------------------------------------------------------------------------
extern "C" void kernel_launch(void* const* d_in, const int* in_sizes, int n_in,
                              void* d_out, int out_size, void* d_ws,
                              size_t ws_size, hipStream_t stream)
{
    const float* x  = (const float*)d_in[0];
    const float* wq = (const float*)d_in[1];
    const float* wk = (const float*)d_in[2];
    const float* wv = (const float*)d_in[3];
    const float* wo = (const float*)d_in[4];
    float* out = (float*)d_out;

    // workspace layout: qkv f32 | k1 f32 | k2 f32 | attn_out f32  (~21 MB)
    float* wsf  = (float*)d_ws;
    float* qkv  = wsf;                                   // 2048*1536 f32
    float* k1   = qkv + (size_t)BS_ * NW_;               // 8192 f32
    float* k2   = k1 + B_ * KVH_ * M_ * DHH_;            // 8192 f32
    float* aout = k2 + B_ * KVH_ * M_ * DHH_;            // 2048*1024 f32

    // 1) fused qkv GEMM, 3-way split / 6 products (score noise ~1e-7;
    //    round-4-proven numerics, round-7 regression reverted)
    dim3 g1(BS_ / 64, NW_ / 64);
    gemm_mfma_kernel<3, 2><<<g1, 256, 0, stream>>>(
        x, wq, wk, wv, KOFF_, VOFF_, qkv, NW_, DM_);
    // 2) RoPE on q,k (numpy-f32 bit-matched)
    rope_kernel<<<(BS_ * (QH_ + KVH_) * DHH_) / 256, 256, 0, stream>>>(qkv);
    // 3) k1/k2 grid sums (f64 accum, f32 store)
    k1k2_kernel<<<32, 256, 0, stream>>>(qkv, k1, k2);
    // 4) two-stage top-k select + 8-key attention (bitonic, f32)
    select_kernel<<<B_ * QH_ * S_ / 4, 256, 0, stream>>>(qkv, k1, k2, aout);
    // 5) output GEMM, plain bf16 (value-grade; cannot affect selection)
    dim3 g2(BS_ / 64, DM_ / 64);
    gemm_mfma_kernel<1, 0><<<g2, 256, 0, stream>>>(
        aout, wo, wo, wo, 1 << 30, 1 << 30, out, DM_, DM_);
}

// Round 9
// 141.721 us; speedup vs baseline: 4.0580x; 1.0046x over previous
//
#include <hip/hip_runtime.h>
#include <hip/hip_bf16.h>
#include <math.h>

// Problem constants (B=2, S=1024, DM=1024, QH=16, KVH=4)
constexpr int B_   = 2;
constexpr int S_   = 1024;
constexpr int DM_  = 1024;
constexpr int QH_  = 16;
constexpr int KVH_ = 4;
constexpr int DH_  = 64;
constexpr int DHH_ = 32;
constexpr int M_   = 32;    // sqrt(S)
constexpr int TOPK_ = 8;
constexpr int BS_  = B_ * S_;                    // 2048
constexpr int NW_  = QH_*DH_ + 2*KVH_*DH_;       // 1536 (q|k|v fused row)
constexpr int KOFF_ = QH_*DH_;                   // 1024
constexpr int VOFF_ = KOFF_ + KVH_*DH_;          // 1280

typedef __attribute__((ext_vector_type(8))) short short8v;   // 8 bf16 (4 VGPR)
typedef __attribute__((ext_vector_type(4))) short short4v;   // 4 bf16 (8B)
typedef __attribute__((ext_vector_type(4))) float float4v;   // MFMA acc

__device__ inline unsigned short bf16_rne(float f) {
    unsigned u = __float_as_uint(f);
    return (unsigned short)((u + 0x7FFFu + ((u >> 16) & 1u)) >> 16);
}
__device__ inline float bf16_back(unsigned short h) {
    return __uint_as_float(((unsigned)h) << 16);
}

// ---------------------------------------------------------------------------
// Precompute LEVELS-deep bf16 split planes of an f32 array (grid-stride by
// float4).  Residual chain identical to the in-kernel split (bit-identical
// scores).  Hoisted out of the GEMM: rocprof r8 showed the qkv GEMM VALU-
// bound (VALUBusy 50% vs MfmaUtil 24%) on split conversion that was
// recomputed 24x (x) / 32x (W) across the grid.
// ---------------------------------------------------------------------------
template<int LEVELS>
__global__ __launch_bounds__(256) void split_kernel(
    const float* __restrict__ src, int n4,
    short* __restrict__ dst, size_t planeStride)
{
    int i = blockIdx.x * 256 + threadIdx.x;
    if (i >= n4) return;
    float4 v = reinterpret_cast<const float4*>(src)[i];
    float f[4] = {v.x, v.y, v.z, v.w};
#pragma unroll
    for (int l = 0; l < LEVELS; ++l) {
        short4v s;
#pragma unroll
        for (int e = 0; e < 4; ++e) {
            unsigned short h = bf16_rne(f[e]);
            s[e] = (short)h;
            f[e] -= bf16_back(h);
        }
        reinterpret_cast<short4v*>(dst + l * planeStride)[i] = s;
    }
}

// ---------------------------------------------------------------------------
// Pre-split MFMA GEMM: C = A @ B^T from bf16 planes (A: [rows][K] per level
// at strideA, B likewise).  64x64 tile, 4 waves (2x2), wave tile 32x32,
// BK=32.  Staging is LEVELS x 16B loads per operand per thread (no VALU
// conversion); LDS layout/swizzle identical to the round-8 kernel (16B
// writes == two 8B writes there: XOR touches only byte bits 4-5).
// ---------------------------------------------------------------------------
template<int LEVELS, int CROSS>
__global__ __launch_bounds__(256) void gemm_presplit_kernel(
    const short* __restrict__ Ab, const short* __restrict__ Bb,
    size_t strideA, size_t strideB,
    float* __restrict__ C, int N, int K)
{
    __shared__ short As[LEVELS * 64 * 32];   // 4 KB per level
    __shared__ short Bs[LEVELS * 64 * 32];
    const int tid = threadIdx.x;
    const int rowBase = blockIdx.x * 64;
    const int colBase = blockIdx.y * 64;
    const int lane = tid & 63, wvi = tid >> 6;
    const int wr = wvi >> 1, wc = wvi & 1;     // wave tile origin /32
    const int fr = lane & 15, fk = lane >> 4;  // fragment row, k-group

    // one 16B staging unit per thread per level: row = tid>>2, c8 = tid&3
    const int srow = tid >> 2, sc8 = tid & 3;
    const size_t aoff = (size_t)(rowBase + srow) * K + sc8 * 8;
    const size_t boff = (size_t)(colBase + srow) * K + sc8 * 8;
    const int sbyte = srow * 64 + ((sc8 * 16) ^ (((srow >> 1) & 3) << 4));

    short8v pa[LEVELS], pb[LEVELS];
#pragma unroll
    for (int l = 0; l < LEVELS; ++l) {
        pa[l] = *reinterpret_cast<const short8v*>(Ab + l * strideA + aoff);
        pb[l] = *reinterpret_cast<const short8v*>(Bb + l * strideB + boff);
    }

    float4v acc[2][2];
#pragma unroll
    for (int mi = 0; mi < 2; ++mi)
#pragma unroll
        for (int ni = 0; ni < 2; ++ni) acc[mi][ni] = (float4v)0.f;

    const int NKC = K >> 5;
    for (int kc = 0; kc < NKC; ++kc) {
#pragma unroll
        for (int l = 0; l < LEVELS; ++l) {
            *reinterpret_cast<short8v*>((char*)As + l * 4096 + sbyte) = pa[l];
            *reinterpret_cast<short8v*>((char*)Bs + l * 4096 + sbyte) = pb[l];
        }
        __syncthreads();
        if (kc + 1 < NKC) {
#pragma unroll
            for (int l = 0; l < LEVELS; ++l) {
                pa[l] = *reinterpret_cast<const short8v*>(
                    Ab + l * strideA + aoff + (size_t)(kc + 1) * 32);
                pb[l] = *reinterpret_cast<const short8v*>(
                    Bb + l * strideB + boff + (size_t)(kc + 1) * 32);
            }
        }
        short8v aF[LEVELS][2];
#pragma unroll
        for (int l = 0; l < LEVELS; ++l)
#pragma unroll
            for (int mi = 0; mi < 2; ++mi) {
                int row = wr * 32 + mi * 16 + fr;
                int byte = l * 4096 + row * 64 +
                           ((fk * 16) ^ (((row >> 1) & 3) << 4));
                aF[l][mi] = *reinterpret_cast<const short8v*>((const char*)As + byte);
            }
#pragma unroll
        for (int lb = 0; lb < LEVELS; ++lb) {
            short8v bF[2];
#pragma unroll
            for (int ni = 0; ni < 2; ++ni) {
                int row = wc * 32 + ni * 16 + fr;
                int byte = lb * 4096 + row * 64 +
                           ((fk * 16) ^ (((row >> 1) & 3) << 4));
                bF[ni] = *reinterpret_cast<const short8v*>((const char*)Bs + byte);
            }
#pragma unroll
            for (int la = 0; la < LEVELS; ++la) {
                if (la + lb > CROSS) continue;
#pragma unroll
                for (int mi = 0; mi < 2; ++mi)
#pragma unroll
                    for (int ni = 0; ni < 2; ++ni)
                        acc[mi][ni] = __builtin_amdgcn_mfma_f32_16x16x32_bf16(
                            aF[la][mi], bF[ni], acc[mi][ni], 0, 0, 0);
            }
        }
        __syncthreads();
    }
#pragma unroll
    for (int mi = 0; mi < 2; ++mi)
#pragma unroll
        for (int ni = 0; ni < 2; ++ni) {
            int row0 = rowBase + wr * 32 + mi * 16 + fk * 4;
            int col  = colBase + wc * 32 + ni * 16 + fr;
#pragma unroll
            for (int j = 0; j < 4; ++j)
                C[(size_t)(row0 + j) * N + col] = acc[mi][ni][j];
        }
}

// ---------------------------------------------------------------------------
// Round-8 in-kernel-split GEMM — kept as the FALLBACK when ws_size is too
// small for the split planes (ws_size is fixed per session -> deterministic).
// ---------------------------------------------------------------------------
template<int LEVELS, int CROSS>
__global__ __launch_bounds__(256) void gemm_mfma_kernel(
    const float* __restrict__ A,
    const float* __restrict__ W0, const float* __restrict__ W1,
    const float* __restrict__ W2, int n1, int n2,
    float* __restrict__ C, int N, int K)
{
    __shared__ short As[LEVELS * 64 * 32];
    __shared__ short Bs[LEVELS * 64 * 32];
    const int tid = threadIdx.x;
    const int rowBase = blockIdx.x * 64;
    const int colBase = blockIdx.y * 64;
    const int lane = tid & 63, wvi = tid >> 6;
    const int wr = wvi >> 1, wc = wvi & 1;
    const int fr = lane & 15, fk = lane >> 4;

    const float* aptr[2]; const float* bptr[2];
    int arow_[2], ac4_[2];
#pragma unroll
    for (int i = 0; i < 2; ++i) {
        int q = i * 256 + tid;
        int row = q >> 3, c4 = q & 7;
        arow_[i] = row; ac4_[i] = c4;
        aptr[i] = A + (size_t)(rowBase + row) * K + c4 * 4;
        int n = colBase + row;
        const float* wrow = (n < n1) ? W0 + (size_t)n * K
                          : (n < n2) ? W1 + (size_t)(n - n1) * K
                                     : W2 + (size_t)(n - n2) * K;
        bptr[i] = wrow + c4 * 4;
    }
    float4 pa[2], pb[2];
#pragma unroll
    for (int i = 0; i < 2; ++i) {
        pa[i] = *reinterpret_cast<const float4*>(aptr[i]);
        pb[i] = *reinterpret_cast<const float4*>(bptr[i]);
    }
    float4v acc[2][2];
#pragma unroll
    for (int mi = 0; mi < 2; ++mi)
#pragma unroll
        for (int ni = 0; ni < 2; ++ni) acc[mi][ni] = (float4v)0.f;

    const int NKC = K >> 5;
    for (int kc = 0; kc < NKC; ++kc) {
#pragma unroll
        for (int i = 0; i < 2; ++i) {
            int row = arow_[i];
            int base = row * 64 + ((ac4_[i] * 8) ^ (((row >> 1) & 3) << 4));
            float fa[4] = {pa[i].x, pa[i].y, pa[i].z, pa[i].w};
            float fb[4] = {pb[i].x, pb[i].y, pb[i].z, pb[i].w};
#pragma unroll
            for (int l = 0; l < LEVELS; ++l) {
                short4v sa, sb;
#pragma unroll
                for (int e = 0; e < 4; ++e) {
                    unsigned short ha = bf16_rne(fa[e]);
                    unsigned short hb = bf16_rne(fb[e]);
                    sa[e] = (short)ha; sb[e] = (short)hb;
                    fa[e] -= bf16_back(ha);
                    fb[e] -= bf16_back(hb);
                }
                *reinterpret_cast<short4v*>((char*)As + l * 4096 + base) = sa;
                *reinterpret_cast<short4v*>((char*)Bs + l * 4096 + base) = sb;
            }
        }
        __syncthreads();
        if (kc + 1 < NKC) {
#pragma unroll
            for (int i = 0; i < 2; ++i) {
                pa[i] = *reinterpret_cast<const float4*>(aptr[i] + (kc+1)*32);
                pb[i] = *reinterpret_cast<const float4*>(bptr[i] + (kc+1)*32);
            }
        }
        short8v aF[LEVELS][2];
#pragma unroll
        for (int l = 0; l < LEVELS; ++l)
#pragma unroll
            for (int mi = 0; mi < 2; ++mi) {
                int row = wr * 32 + mi * 16 + fr;
                int byte = l * 4096 + row * 64 +
                           ((fk * 16) ^ (((row >> 1) & 3) << 4));
                aF[l][mi] = *reinterpret_cast<const short8v*>((const char*)As + byte);
            }
#pragma unroll
        for (int lb = 0; lb < LEVELS; ++lb) {
            short8v bF[2];
#pragma unroll
            for (int ni = 0; ni < 2; ++ni) {
                int row = wc * 32 + ni * 16 + fr;
                int byte = lb * 4096 + row * 64 +
                           ((fk * 16) ^ (((row >> 1) & 3) << 4));
                bF[ni] = *reinterpret_cast<const short8v*>((const char*)Bs + byte);
            }
#pragma unroll
            for (int la = 0; la < LEVELS; ++la) {
                if (la + lb > CROSS) continue;
#pragma unroll
                for (int mi = 0; mi < 2; ++mi)
#pragma unroll
                    for (int ni = 0; ni < 2; ++ni)
                        acc[mi][ni] = __builtin_amdgcn_mfma_f32_16x16x32_bf16(
                            aF[la][mi], bF[ni], acc[mi][ni], 0, 0, 0);
            }
        }
        __syncthreads();
    }
#pragma unroll
    for (int mi = 0; mi < 2; ++mi)
#pragma unroll
        for (int ni = 0; ni < 2; ++ni) {
            int row0 = rowBase + wr * 32 + mi * 16 + fk * 4;
            int col  = colBase + wc * 32 + ni * 16 + fr;
#pragma unroll
            for (int j = 0; j < 4; ++j)
                C[(size_t)(row0 + j) * N + col] = acc[mi][ni][j];
        }
}

// ---------------------------------------------------------------------------
// RoPE in-place, bit-matching the numpy f32 reference.
// ---------------------------------------------------------------------------
__global__ __launch_bounds__(256) void rope_kernel(float* __restrict__ qkv)
{
    int id = blockIdx.x * 256 + threadIdx.x;   // BS * 20 * 32 threads
    int d  = id & 31;
    int r  = id >> 5;
    int h  = r % (QH_ + KVH_);
    int bs = r / (QH_ + KVH_);
    int s  = bs & (S_ - 1);
    float* base = qkv + (size_t)bs * NW_ +
                  (h < QH_ ? h * DH_ : KOFF_ + (h - QH_) * DH_);
    double e = (double)d * (1.0 / 32.0);
    float pf = (float)pow(10000.0, e);         // == correctly-rounded powf
    float inv_freq = __fdiv_rn(1.0f, pf);      // numpy's 2nd f32 rounding
    float ang = __fmul_rn((float)s, inv_freq);
    double sn64, cs64;
    sincos((double)ang, &sn64, &cs64);
    float cs = (float)cs64;
    float sn = (float)sn64;
    float x1 = base[d];
    float x2 = base[d + DHH_];
    base[d]        = __fadd_rn(__fmul_rn(x1, cs), __fmul_rn(-x2, sn));
    base[d + DHH_] = __fadd_rn(__fmul_rn(x2, cs), __fmul_rn(x1, sn));
}

// ---------------------------------------------------------------------------
// k1/k2 grid sums: f64 accum, f32 store.  32 blocks.
// ---------------------------------------------------------------------------
__global__ __launch_bounds__(256) void k1k2_kernel(
    const float* __restrict__ qkv, float* __restrict__ k1,
    float* __restrict__ k2)
{
    int blk   = blockIdx.x;
    int bkv   = blk >> 2;
    int chunk = blk & 3;
    int b = bkv >> 2, kv = bkv & 3;
    int tid = threadIdx.x;
    int d  = tid & 31;
    int m  = chunk * 8 + (tid >> 5);
    const float* kbase = qkv + (size_t)b * S_ * NW_ + KOFF_ + kv * DH_;
    double s1 = 0., s2 = 0.;
    for (int mc = 0; mc < M_; ++mc) {
        s1 += (double)kbase[(size_t)(m * M_ + mc) * NW_ + d];
        s2 += (double)kbase[(size_t)(mc * M_ + m) * NW_ + DHH_ + d];
    }
    k1[((b * KVH_ + kv) * M_ + m) * DHH_ + d] = (float)s1;
    k2[((b * KVH_ + kv) * M_ + m) * DHH_ + d] = (float)s2;
}

// ---------------------------------------------------------------------------
// Select + attention, bitonic-sort selection (round-6 verified).  BF16OUT
// writes aout as bf16 so the out GEMM can stage it without conversion.
// ---------------------------------------------------------------------------
template<bool BF16OUT>
__global__ __launch_bounds__(256) void select_kernel(
    const float* __restrict__ qkv,
    const float* __restrict__ k1g, const float* __restrict__ k2g,
    void* __restrict__ aout)
{
    __shared__ float k1s[M_][DHH_ + 1];
    __shared__ float k2s[M_][DHH_ + 1];
    __shared__ float qs[4][DH_];

    const int tid = threadIdx.x;
    const int bh  = blockIdx.x >> 8;
    const int s0  = (blockIdx.x & 255) << 2;
    const int b   = bh >> 4;
    const int h   = bh & 15;
    const int kv  = h >> 2;

    const int kbase = (b * KVH_ + kv) * M_ * DHH_;
    for (int i = tid; i < M_ * DHH_; i += 256) {
        k1s[i >> 5][i & 31] = k1g[kbase + i];
        k2s[i >> 5][i & 31] = k2g[kbase + i];
    }

    const int w    = tid >> 6;
    const int lane = tid & 63;
    const int s    = s0 + w;
    const float* qrow = qkv + (size_t)(b * S_ + s) * NW_ + h * DH_;
    qs[w][lane] = qrow[lane];
    __syncthreads();

    const int m = lane & 31;
    const bool hi = lane >= 32;
    float v1 = 0.f;
    {
        const float* krow = hi ? &k2s[m][0] : &k1s[m][0];
        const float* qq   = &qs[w][hi ? DHH_ : 0];
#pragma unroll
        for (int d = 0; d < DHH_; ++d) v1 = fmaf(qq[d], krow[d], v1);
    }
    int i1 = m;

    const int l5 = lane & 31;
#pragma unroll
    for (int k = 2; k <= 32; k <<= 1) {
#pragma unroll
        for (int j = k >> 1; j > 0; j >>= 1) {
            float ov = __shfl_xor(v1, j);
            int   oi = __shfl_xor(i1, j);
            bool gt    = (v1 > ov) || (v1 == ov && i1 < oi);
            bool dirD  = ((l5 & k) == 0);
            bool lower = ((lane & j) == 0);
            if (gt != (dirD == lower)) { v1 = ov; i1 = oi; }
        }
    }

    float av = __shfl(v1, lane >> 3);
    float bv = __shfl(v1, 32 + (lane & 7));
    float v2 = av + bv;
    int   c2 = lane;
#pragma unroll
    for (int k = 2; k <= 64; k <<= 1) {
#pragma unroll
        for (int j = k >> 1; j > 0; j >>= 1) {
            float ov = __shfl_xor(v2, j);
            int   oc = __shfl_xor(c2, j);
            bool gt    = (v2 > ov) || (v2 == ov && c2 < oc);
            bool dirD  = ((lane & k) == 0);
            bool lower = ((lane & j) == 0);
            if (gt != (dirD == lower)) { v2 = ov; c2 = oc; }
        }
    }

    float vmax = __shfl(v2, 0);
    float e = (lane < 8) ? expf((v2 - vmax) * 0.125f) : 0.f;
    float sum = e;
#pragma unroll
    for (int msk = 1; msk <= 4; msk <<= 1) sum += __shfl_xor(sum, msk);
    float wn = e / sum;

    const float* vbase = qkv + (size_t)b * S_ * NW_ + VOFF_ + kv * DH_ + lane;
    float o = 0.f;
#pragma unroll
    for (int t = 0; t < TOPK_; ++t) {
        float wt  = __shfl(wn, t);
        int   ct  = __shfl(c2, t);
        int   row = __shfl(i1, ct >> 3);
        int   col = __shfl(i1, 32 + (ct & 7));
        o = fmaf(wt, vbase[(size_t)(row * M_ + col) * NW_], o);
    }
    size_t oidx = (size_t)(b * S_ + s) * (QH_ * DH_) + h * DH_ + lane;
    if (BF16OUT) ((short*)aout)[oidx] = (short)bf16_rne(o);
    else         ((float*)aout)[oidx] = o;
}

// ---------------------------------------------------------------------------
extern "C" void kernel_launch(void* const* d_in, const int* in_sizes, int n_in,
                              void* d_out, int out_size, void* d_ws,
                              size_t ws_size, hipStream_t stream)
{
    const float* x  = (const float*)d_in[0];
    const float* wq = (const float*)d_in[1];
    const float* wk = (const float*)d_in[2];
    const float* wv = (const float*)d_in[3];
    const float* wo = (const float*)d_in[4];
    float* out = (float*)d_out;

    float* wsf = (float*)d_ws;
    float* qkv = wsf;                                    // 2048*1536 f32
    float* k1  = qkv + (size_t)BS_ * NW_;                // 8192 f32
    float* k2  = k1 + B_ * KVH_ * M_ * DHH_;             // 8192 f32

    const bool fast = ws_size >= 40960000ull;            // split planes fit?

    if (fast) {
        short* xs  = (short*)(k2 + B_ * KVH_ * M_ * DHH_);   // 3 planes x
        short* wsp = xs  + (size_t)3 * BS_ * DM_;            // 3 planes w
        short* wob = wsp + (size_t)3 * NW_ * DM_;            // 1 plane wo
        short* aob = wob + (size_t)DM_ * DM_;                // aout bf16

        // 0) precompute split planes (bandwidth-bound, ~8 us total)
        split_kernel<3><<<BS_ * DM_ / 1024, 256, 0, stream>>>(
            x, BS_ * DM_ / 4, xs, (size_t)BS_ * DM_);
        split_kernel<3><<<KOFF_ * DM_ / 1024, 256, 0, stream>>>(
            wq, KOFF_ * DM_ / 4, wsp, (size_t)NW_ * DM_);
        split_kernel<3><<<(VOFF_-KOFF_) * DM_ / 1024, 256, 0, stream>>>(
            wk, (VOFF_-KOFF_) * DM_ / 4, wsp + (size_t)KOFF_ * DM_,
            (size_t)NW_ * DM_);
        split_kernel<3><<<(NW_-VOFF_) * DM_ / 1024, 256, 0, stream>>>(
            wv, (NW_-VOFF_) * DM_ / 4, wsp + (size_t)VOFF_ * DM_,
            (size_t)NW_ * DM_);
        split_kernel<1><<<DM_ * DM_ / 1024, 256, 0, stream>>>(
            wo, DM_ * DM_ / 4, wob, 0);

        // 1) fused qkv GEMM, 6 products from pre-split planes
        dim3 g1(BS_ / 64, NW_ / 64);
        gemm_presplit_kernel<3, 2><<<g1, 256, 0, stream>>>(
            xs, wsp, (size_t)BS_ * DM_, (size_t)NW_ * DM_, qkv, NW_, DM_);
        // 2) RoPE
        rope_kernel<<<(BS_ * (QH_ + KVH_) * DHH_) / 256, 256, 0, stream>>>(qkv);
        // 3) k1/k2
        k1k2_kernel<<<32, 256, 0, stream>>>(qkv, k1, k2);
        // 4) select (writes bf16 aout)
        select_kernel<true><<<B_ * QH_ * S_ / 4, 256, 0, stream>>>(
            qkv, k1, k2, aob);
        // 5) output GEMM, plain bf16 from aout/wo planes
        dim3 g2(BS_ / 64, DM_ / 64);
        gemm_presplit_kernel<1, 0><<<g2, 256, 0, stream>>>(
            aob, wob, 0, 0, out, DM_, DM_);
    } else {
        // -------- round-8 fallback (21 MB workspace) --------
        float* aout = k2 + B_ * KVH_ * M_ * DHH_;
        dim3 g1(BS_ / 64, NW_ / 64);
        gemm_mfma_kernel<3, 2><<<g1, 256, 0, stream>>>(
            x, wq, wk, wv, KOFF_, VOFF_, qkv, NW_, DM_);
        rope_kernel<<<(BS_ * (QH_ + KVH_) * DHH_) / 256, 256, 0, stream>>>(qkv);
        k1k2_kernel<<<32, 256, 0, stream>>>(qkv, k1, k2);
        select_kernel<false><<<B_ * QH_ * S_ / 4, 256, 0, stream>>>(
            qkv, k1, k2, aout);
        dim3 g2(BS_ / 64, DM_ / 64);
        gemm_mfma_kernel<1, 0><<<g2, 256, 0, stream>>>(
            aout, wo, wo, wo, 1 << 30, 1 << 30, out, DM_, DM_);
    }
}

// Round 10
// 133.735 us; speedup vs baseline: 4.3003x; 1.0597x over previous
//
#include <hip/hip_runtime.h>
#include <hip/hip_bf16.h>
#include <math.h>

// Problem constants (B=2, S=1024, DM=1024, QH=16, KVH=4)
constexpr int B_   = 2;
constexpr int S_   = 1024;
constexpr int DM_  = 1024;
constexpr int QH_  = 16;
constexpr int KVH_ = 4;
constexpr int DH_  = 64;
constexpr int DHH_ = 32;
constexpr int M_   = 32;    // sqrt(S)
constexpr int TOPK_ = 8;
constexpr int BS_  = B_ * S_;                    // 2048
constexpr int NW_  = QH_*DH_ + 2*KVH_*DH_;       // 1536 (q|k|v fused row)
constexpr int KOFF_ = QH_*DH_;                   // 1024
constexpr int VOFF_ = KOFF_ + KVH_*DH_;          // 1280

typedef __attribute__((ext_vector_type(8))) short short8v;   // 8 bf16 (4 VGPR)
typedef __attribute__((ext_vector_type(4))) short short4v;   // 4 bf16 (8B)
typedef __attribute__((ext_vector_type(4))) float float4v;   // MFMA acc

__device__ inline unsigned short bf16_rne(float f) {
    unsigned u = __float_as_uint(f);
    return (unsigned short)((u + 0x7FFFu + ((u >> 16) & 1u)) >> 16);
}
__device__ inline float bf16_back(unsigned short h) {
    return __uint_as_float(((unsigned)h) << 16);
}

// ---------------------------------------------------------------------------
// Split helpers (residual chain identical across all users -> bit-identical
// scores vs rounds 4/8/9).
// ---------------------------------------------------------------------------
template<int LEVELS>
__device__ inline void split_one(const float* __restrict__ src, int i,
                                 short* __restrict__ dst, size_t planeStride)
{
    float4 v = reinterpret_cast<const float4*>(src)[i];
    float f[4] = {v.x, v.y, v.z, v.w};
#pragma unroll
    for (int l = 0; l < LEVELS; ++l) {
        short4v s;
#pragma unroll
        for (int e = 0; e < 4; ++e) {
            unsigned short h = bf16_rne(f[e]);
            s[e] = (short)h;
            f[e] -= bf16_back(h);
        }
        reinterpret_cast<short4v*>(dst + l * planeStride)[i] = s;
    }
}

// One fused kernel for all 5 split regions (was 5 launches ~= 10-15 us of
// launch overhead; region branch is block-uniform except at boundaries).
__global__ __launch_bounds__(256) void split_all_kernel(
    const float* __restrict__ x,  const float* __restrict__ wq,
    const float* __restrict__ wk, const float* __restrict__ wv,
    const float* __restrict__ wo,
    short* __restrict__ xs, short* __restrict__ wsp, short* __restrict__ wob)
{
    constexpr int E0 = BS_ * DM_ / 4;                 // x      (524288)
    constexpr int E1 = E0 + KOFF_ * DM_ / 4;          // wq
    constexpr int E2 = E1 + (VOFF_ - KOFF_) * DM_ / 4;// wk
    constexpr int E3 = E2 + (NW_ - VOFF_) * DM_ / 4;  // wv
    constexpr int E4 = E3 + DM_ * DM_ / 4;            // wo     (1179648)
    int i = blockIdx.x * 256 + threadIdx.x;
    if (i < E0)      split_one<3>(x,  i,      xs,  (size_t)BS_ * DM_);
    else if (i < E1) split_one<3>(wq, i - E0, wsp, (size_t)NW_ * DM_);
    else if (i < E2) split_one<3>(wk, i - E1, wsp + (size_t)KOFF_ * DM_,
                                  (size_t)NW_ * DM_);
    else if (i < E3) split_one<3>(wv, i - E2, wsp + (size_t)VOFF_ * DM_,
                                  (size_t)NW_ * DM_);
    else if (i < E4) split_one<1>(wo, i - E3, wob, 0);
}

// ---------------------------------------------------------------------------
// Pre-split MFMA GEMM (round-9 verified): C = A @ B^T from bf16 planes.
// 64x64 tile, 4 waves (2x2), wave tile 32x32, BK=32, XOR-swizzled LDS.
// ---------------------------------------------------------------------------
template<int LEVELS, int CROSS>
__global__ __launch_bounds__(256) void gemm_presplit_kernel(
    const short* __restrict__ Ab, const short* __restrict__ Bb,
    size_t strideA, size_t strideB,
    float* __restrict__ C, int N, int K)
{
    __shared__ short As[LEVELS * 64 * 32];   // 4 KB per level
    __shared__ short Bs[LEVELS * 64 * 32];
    const int tid = threadIdx.x;
    const int rowBase = blockIdx.x * 64;
    const int colBase = blockIdx.y * 64;
    const int lane = tid & 63, wvi = tid >> 6;
    const int wr = wvi >> 1, wc = wvi & 1;     // wave tile origin /32
    const int fr = lane & 15, fk = lane >> 4;  // fragment row, k-group

    const int srow = tid >> 2, sc8 = tid & 3;
    const size_t aoff = (size_t)(rowBase + srow) * K + sc8 * 8;
    const size_t boff = (size_t)(colBase + srow) * K + sc8 * 8;
    const int sbyte = srow * 64 + ((sc8 * 16) ^ (((srow >> 1) & 3) << 4));

    short8v pa[LEVELS], pb[LEVELS];
#pragma unroll
    for (int l = 0; l < LEVELS; ++l) {
        pa[l] = *reinterpret_cast<const short8v*>(Ab + l * strideA + aoff);
        pb[l] = *reinterpret_cast<const short8v*>(Bb + l * strideB + boff);
    }

    float4v acc[2][2];
#pragma unroll
    for (int mi = 0; mi < 2; ++mi)
#pragma unroll
        for (int ni = 0; ni < 2; ++ni) acc[mi][ni] = (float4v)0.f;

    const int NKC = K >> 5;
    for (int kc = 0; kc < NKC; ++kc) {
#pragma unroll
        for (int l = 0; l < LEVELS; ++l) {
            *reinterpret_cast<short8v*>((char*)As + l * 4096 + sbyte) = pa[l];
            *reinterpret_cast<short8v*>((char*)Bs + l * 4096 + sbyte) = pb[l];
        }
        __syncthreads();
        if (kc + 1 < NKC) {
#pragma unroll
            for (int l = 0; l < LEVELS; ++l) {
                pa[l] = *reinterpret_cast<const short8v*>(
                    Ab + l * strideA + aoff + (size_t)(kc + 1) * 32);
                pb[l] = *reinterpret_cast<const short8v*>(
                    Bb + l * strideB + boff + (size_t)(kc + 1) * 32);
            }
        }
        short8v aF[LEVELS][2];
#pragma unroll
        for (int l = 0; l < LEVELS; ++l)
#pragma unroll
            for (int mi = 0; mi < 2; ++mi) {
                int row = wr * 32 + mi * 16 + fr;
                int byte = l * 4096 + row * 64 +
                           ((fk * 16) ^ (((row >> 1) & 3) << 4));
                aF[l][mi] = *reinterpret_cast<const short8v*>((const char*)As + byte);
            }
#pragma unroll
        for (int lb = 0; lb < LEVELS; ++lb) {
            short8v bF[2];
#pragma unroll
            for (int ni = 0; ni < 2; ++ni) {
                int row = wc * 32 + ni * 16 + fr;
                int byte = lb * 4096 + row * 64 +
                           ((fk * 16) ^ (((row >> 1) & 3) << 4));
                bF[ni] = *reinterpret_cast<const short8v*>((const char*)Bs + byte);
            }
#pragma unroll
            for (int la = 0; la < LEVELS; ++la) {
                if (la + lb > CROSS) continue;
#pragma unroll
                for (int mi = 0; mi < 2; ++mi)
#pragma unroll
                    for (int ni = 0; ni < 2; ++ni)
                        acc[mi][ni] = __builtin_amdgcn_mfma_f32_16x16x32_bf16(
                            aF[la][mi], bF[ni], acc[mi][ni], 0, 0, 0);
            }
        }
        __syncthreads();
    }
#pragma unroll
    for (int mi = 0; mi < 2; ++mi)
#pragma unroll
        for (int ni = 0; ni < 2; ++ni) {
            int row0 = rowBase + wr * 32 + mi * 16 + fk * 4;
            int col  = colBase + wc * 32 + ni * 16 + fr;
#pragma unroll
            for (int j = 0; j < 4; ++j)
                C[(size_t)(row0 + j) * N + col] = acc[mi][ni][j];
        }
}

// ---------------------------------------------------------------------------
// Round-8 in-kernel-split GEMM — FALLBACK when ws_size too small.
// ---------------------------------------------------------------------------
template<int LEVELS, int CROSS>
__global__ __launch_bounds__(256) void gemm_mfma_kernel(
    const float* __restrict__ A,
    const float* __restrict__ W0, const float* __restrict__ W1,
    const float* __restrict__ W2, int n1, int n2,
    float* __restrict__ C, int N, int K)
{
    __shared__ short As[LEVELS * 64 * 32];
    __shared__ short Bs[LEVELS * 64 * 32];
    const int tid = threadIdx.x;
    const int rowBase = blockIdx.x * 64;
    const int colBase = blockIdx.y * 64;
    const int lane = tid & 63, wvi = tid >> 6;
    const int wr = wvi >> 1, wc = wvi & 1;
    const int fr = lane & 15, fk = lane >> 4;

    const float* aptr[2]; const float* bptr[2];
    int arow_[2], ac4_[2];
#pragma unroll
    for (int i = 0; i < 2; ++i) {
        int q = i * 256 + tid;
        int row = q >> 3, c4 = q & 7;
        arow_[i] = row; ac4_[i] = c4;
        aptr[i] = A + (size_t)(rowBase + row) * K + c4 * 4;
        int n = colBase + row;
        const float* wrow = (n < n1) ? W0 + (size_t)n * K
                          : (n < n2) ? W1 + (size_t)(n - n1) * K
                                     : W2 + (size_t)(n - n2) * K;
        bptr[i] = wrow + c4 * 4;
    }
    float4 pa[2], pb[2];
#pragma unroll
    for (int i = 0; i < 2; ++i) {
        pa[i] = *reinterpret_cast<const float4*>(aptr[i]);
        pb[i] = *reinterpret_cast<const float4*>(bptr[i]);
    }
    float4v acc[2][2];
#pragma unroll
    for (int mi = 0; mi < 2; ++mi)
#pragma unroll
        for (int ni = 0; ni < 2; ++ni) acc[mi][ni] = (float4v)0.f;

    const int NKC = K >> 5;
    for (int kc = 0; kc < NKC; ++kc) {
#pragma unroll
        for (int i = 0; i < 2; ++i) {
            int row = arow_[i];
            int base = row * 64 + ((ac4_[i] * 8) ^ (((row >> 1) & 3) << 4));
            float fa[4] = {pa[i].x, pa[i].y, pa[i].z, pa[i].w};
            float fb[4] = {pb[i].x, pb[i].y, pb[i].z, pb[i].w};
#pragma unroll
            for (int l = 0; l < LEVELS; ++l) {
                short4v sa, sb;
#pragma unroll
                for (int e = 0; e < 4; ++e) {
                    unsigned short ha = bf16_rne(fa[e]);
                    unsigned short hb = bf16_rne(fb[e]);
                    sa[e] = (short)ha; sb[e] = (short)hb;
                    fa[e] -= bf16_back(ha);
                    fb[e] -= bf16_back(hb);
                }
                *reinterpret_cast<short4v*>((char*)As + l * 4096 + base) = sa;
                *reinterpret_cast<short4v*>((char*)Bs + l * 4096 + base) = sb;
            }
        }
        __syncthreads();
        if (kc + 1 < NKC) {
#pragma unroll
            for (int i = 0; i < 2; ++i) {
                pa[i] = *reinterpret_cast<const float4*>(aptr[i] + (kc+1)*32);
                pb[i] = *reinterpret_cast<const float4*>(bptr[i] + (kc+1)*32);
            }
        }
        short8v aF[LEVELS][2];
#pragma unroll
        for (int l = 0; l < LEVELS; ++l)
#pragma unroll
            for (int mi = 0; mi < 2; ++mi) {
                int row = wr * 32 + mi * 16 + fr;
                int byte = l * 4096 + row * 64 +
                           ((fk * 16) ^ (((row >> 1) & 3) << 4));
                aF[l][mi] = *reinterpret_cast<const short8v*>((const char*)As + byte);
            }
#pragma unroll
        for (int lb = 0; lb < LEVELS; ++lb) {
            short8v bF[2];
#pragma unroll
            for (int ni = 0; ni < 2; ++ni) {
                int row = wc * 32 + ni * 16 + fr;
                int byte = lb * 4096 + row * 64 +
                           ((fk * 16) ^ (((row >> 1) & 3) << 4));
                bF[ni] = *reinterpret_cast<const short8v*>((const char*)Bs + byte);
            }
#pragma unroll
            for (int la = 0; la < LEVELS; ++la) {
                if (la + lb > CROSS) continue;
#pragma unroll
                for (int mi = 0; mi < 2; ++mi)
#pragma unroll
                    for (int ni = 0; ni < 2; ++ni)
                        acc[mi][ni] = __builtin_amdgcn_mfma_f32_16x16x32_bf16(
                            aF[la][mi], bF[ni], acc[mi][ni], 0, 0, 0);
            }
        }
        __syncthreads();
    }
#pragma unroll
    for (int mi = 0; mi < 2; ++mi)
#pragma unroll
        for (int ni = 0; ni < 2; ++ni) {
            int row0 = rowBase + wr * 32 + mi * 16 + fk * 4;
            int col  = colBase + wc * 32 + ni * 16 + fr;
#pragma unroll
            for (int j = 0; j < 4; ++j)
                C[(size_t)(row0 + j) * N + col] = acc[mi][ni][j];
        }
}

// ---------------------------------------------------------------------------
// RoPE in-place, bit-matching the numpy f32 reference.
// ---------------------------------------------------------------------------
__global__ __launch_bounds__(256) void rope_kernel(float* __restrict__ qkv)
{
    int id = blockIdx.x * 256 + threadIdx.x;   // BS * 20 * 32 threads
    int d  = id & 31;
    int r  = id >> 5;
    int h  = r % (QH_ + KVH_);
    int bs = r / (QH_ + KVH_);
    int s  = bs & (S_ - 1);
    float* base = qkv + (size_t)bs * NW_ +
                  (h < QH_ ? h * DH_ : KOFF_ + (h - QH_) * DH_);
    double e = (double)d * (1.0 / 32.0);
    float pf = (float)pow(10000.0, e);         // == correctly-rounded powf
    float inv_freq = __fdiv_rn(1.0f, pf);      // numpy's 2nd f32 rounding
    float ang = __fmul_rn((float)s, inv_freq);
    double sn64, cs64;
    sincos((double)ang, &sn64, &cs64);
    float cs = (float)cs64;
    float sn = (float)sn64;
    float x1 = base[d];
    float x2 = base[d + DHH_];
    base[d]        = __fadd_rn(__fmul_rn(x1, cs), __fmul_rn(-x2, sn));
    base[d + DHH_] = __fadd_rn(__fmul_rn(x2, cs), __fmul_rn(x1, sn));
}

// ---------------------------------------------------------------------------
// k1/k2 grid sums: f64 accum, f32 store.  32 blocks.
// ---------------------------------------------------------------------------
__global__ __launch_bounds__(256) void k1k2_kernel(
    const float* __restrict__ qkv, float* __restrict__ k1,
    float* __restrict__ k2)
{
    int blk   = blockIdx.x;
    int bkv   = blk >> 2;
    int chunk = blk & 3;
    int b = bkv >> 2, kv = bkv & 3;
    int tid = threadIdx.x;
    int d  = tid & 31;
    int m  = chunk * 8 + (tid >> 5);
    const float* kbase = qkv + (size_t)b * S_ * NW_ + KOFF_ + kv * DH_;
    double s1 = 0., s2 = 0.;
    for (int mc = 0; mc < M_; ++mc) {
        s1 += (double)kbase[(size_t)(m * M_ + mc) * NW_ + d];
        s2 += (double)kbase[(size_t)(mc * M_ + m) * NW_ + DHH_ + d];
    }
    k1[((b * KVH_ + kv) * M_ + m) * DHH_ + d] = (float)s1;
    k2[((b * KVH_ + kv) * M_ + m) * DHH_ + d] = (float)s2;
}

// ---------------------------------------------------------------------------
// Select + attention, bitonic, BATCHED 4 s-problems per wave.  Round-9
// profile: 53 us at VALUBusy 43% -- latency-bound on the 36-step dependent
// shuffle chain (DS-pipe ~25cyc each), 1 problem/wave.  Batching gives the
// chain 4-way ILP; per-s arithmetic (dot order, sort network, softmax,
// gather) is bit-identical -> selection provably unchanged.
// Block = 4 waves x 4 s = 16 s; grid = B*QH*S/16 = 2048.
// ---------------------------------------------------------------------------
template<bool BF16OUT>
__global__ __launch_bounds__(256) void select4_kernel(
    const float* __restrict__ qkv,
    const float* __restrict__ k1g, const float* __restrict__ k2g,
    void* __restrict__ aout)
{
    __shared__ float k1s[M_][DHH_ + 1];
    __shared__ float k2s[M_][DHH_ + 1];
    __shared__ float qs[16][DH_];

    const int tid = threadIdx.x;
    const int bh  = blockIdx.x >> 6;           // 64 blocks per (b,h)
    const int s0  = (blockIdx.x & 63) << 4;
    const int b   = bh >> 4;
    const int h   = bh & 15;
    const int kv  = h >> 2;

    const int kbase = (b * KVH_ + kv) * M_ * DHH_;
    for (int i = tid; i < M_ * DHH_; i += 256) {
        k1s[i >> 5][i & 31] = k1g[kbase + i];
        k2s[i >> 5][i & 31] = k2g[kbase + i];
    }
    for (int i = tid; i < 16 * DH_; i += 256) {
        int r = i >> 6;
        qs[r][i & 63] = qkv[(size_t)(b * S_ + s0 + r) * NW_ + h * DH_ + (i & 63)];
    }
    const int w = tid >> 6, lane = tid & 63;
    __syncthreads();

    // ---- stage-1 dots: 4 independent FMA chains
    const int m = lane & 31;
    const bool hi = lane >= 32;
    const float* krow = hi ? &k2s[m][0] : &k1s[m][0];
    const int qoff = hi ? DHH_ : 0;

    float v1[4]; int i1[4];
#pragma unroll
    for (int u = 0; u < 4; ++u) { v1[u] = 0.f; i1[u] = m; }
#pragma unroll
    for (int d = 0; d < DHH_; ++d) {
        float kd = krow[d];
#pragma unroll
        for (int u = 0; u < 4; ++u)
            v1[u] = fmaf(qs[w * 4 + u][qoff + d], kd, v1[u]);
    }

    // ---- bitonic sort desc within each 32-half (x4 interleaved)
    const int l5 = lane & 31;
#pragma unroll
    for (int k = 2; k <= 32; k <<= 1) {
#pragma unroll
        for (int j = k >> 1; j > 0; j >>= 1) {
            float ov[4]; int oi[4];
#pragma unroll
            for (int u = 0; u < 4; ++u) {
                ov[u] = __shfl_xor(v1[u], j);
                oi[u] = __shfl_xor(i1[u], j);
            }
            const bool dirD  = ((l5 & k) == 0);
            const bool lower = ((lane & j) == 0);
#pragma unroll
            for (int u = 0; u < 4; ++u) {
                bool gt = (v1[u] > ov[u]) || (v1[u] == ov[u] && i1[u] < oi[u]);
                if (gt != (dirD == lower)) { v1[u] = ov[u]; i1[u] = oi[u]; }
            }
        }
    }
    // lanes 0-7: rank-t of s1 (a, idx1); lanes 32-39: rank-t of s2 (b, idx2)

    // ---- stage-2: 64 candidates c=i*8+j, full-wave sort (x4 interleaved)
    float v2[4]; int c2[4];
#pragma unroll
    for (int u = 0; u < 4; ++u) {
        float av = __shfl(v1[u], lane >> 3);
        float bv = __shfl(v1[u], 32 + (lane & 7));
        v2[u] = av + bv; c2[u] = lane;
    }
#pragma unroll
    for (int k = 2; k <= 64; k <<= 1) {
#pragma unroll
        for (int j = k >> 1; j > 0; j >>= 1) {
            float ov[4]; int oc[4];
#pragma unroll
            for (int u = 0; u < 4; ++u) {
                ov[u] = __shfl_xor(v2[u], j);
                oc[u] = __shfl_xor(c2[u], j);
            }
            const bool dirD  = ((lane & k) == 0);
            const bool lower = ((lane & j) == 0);
#pragma unroll
            for (int u = 0; u < 4; ++u) {
                bool gt = (v2[u] > ov[u]) || (v2[u] == ov[u] && c2[u] < oc[u]);
                if (gt != (dirD == lower)) { v2[u] = ov[u]; c2[u] = oc[u]; }
            }
        }
    }

    // ---- softmax over 8 + weighted gather, per u
    const float* vbase = qkv + (size_t)b * S_ * NW_ + VOFF_ + kv * DH_ + lane;
#pragma unroll
    for (int u = 0; u < 4; ++u) {
        float vmax = __shfl(v2[u], 0);
        float e = (lane < 8) ? expf((v2[u] - vmax) * 0.125f) : 0.f;
        float sum = e;
#pragma unroll
        for (int msk = 1; msk <= 4; msk <<= 1) sum += __shfl_xor(sum, msk);
        float wn = e / sum;
        float o = 0.f;
#pragma unroll
        for (int t = 0; t < TOPK_; ++t) {
            float wt  = __shfl(wn, t);
            int   ct  = __shfl(c2[u], t);
            int   row = __shfl(i1[u], ct >> 3);
            int   col = __shfl(i1[u], 32 + (ct & 7));
            o = fmaf(wt, vbase[(size_t)(row * M_ + col) * NW_], o);
        }
        size_t oidx = (size_t)(b * S_ + s0 + w * 4 + u) * (QH_ * DH_)
                    + h * DH_ + lane;
        if (BF16OUT) ((short*)aout)[oidx] = (short)bf16_rne(o);
        else         ((float*)aout)[oidx] = o;
    }
}

// ---------------------------------------------------------------------------
extern "C" void kernel_launch(void* const* d_in, const int* in_sizes, int n_in,
                              void* d_out, int out_size, void* d_ws,
                              size_t ws_size, hipStream_t stream)
{
    const float* x  = (const float*)d_in[0];
    const float* wq = (const float*)d_in[1];
    const float* wk = (const float*)d_in[2];
    const float* wv = (const float*)d_in[3];
    const float* wo = (const float*)d_in[4];
    float* out = (float*)d_out;

    float* wsf = (float*)d_ws;
    float* qkv = wsf;                                    // 2048*1536 f32
    float* k1  = qkv + (size_t)BS_ * NW_;                // 8192 f32
    float* k2  = k1 + B_ * KVH_ * M_ * DHH_;             // 8192 f32

    const bool fast = ws_size >= 40960000ull;            // split planes fit?

    if (fast) {
        short* xs  = (short*)(k2 + B_ * KVH_ * M_ * DHH_);   // 3 planes x
        short* wsp = xs  + (size_t)3 * BS_ * DM_;            // 3 planes w
        short* wob = wsp + (size_t)3 * NW_ * DM_;            // 1 plane wo
        short* aob = wob + (size_t)DM_ * DM_;                // aout bf16

        // 0) all split planes in ONE launch (was 5)
        constexpr int NSLOT = (BS_*DM_ + KOFF_*DM_ + (VOFF_-KOFF_)*DM_ +
                               (NW_-VOFF_)*DM_ + DM_*DM_) / 4;   // 1179648
        split_all_kernel<<<(NSLOT + 255) / 256, 256, 0, stream>>>(
            x, wq, wk, wv, wo, xs, wsp, wob);

        // 1) fused qkv GEMM, 6 products from pre-split planes
        dim3 g1(BS_ / 64, NW_ / 64);
        gemm_presplit_kernel<3, 2><<<g1, 256, 0, stream>>>(
            xs, wsp, (size_t)BS_ * DM_, (size_t)NW_ * DM_, qkv, NW_, DM_);
        // 2) RoPE
        rope_kernel<<<(BS_ * (QH_ + KVH_) * DHH_) / 256, 256, 0, stream>>>(qkv);
        // 3) k1/k2
        k1k2_kernel<<<32, 256, 0, stream>>>(qkv, k1, k2);
        // 4) select, 4 s per wave (writes bf16 aout)
        select4_kernel<true><<<B_ * QH_ * S_ / 16, 256, 0, stream>>>(
            qkv, k1, k2, aob);
        // 5) output GEMM, plain bf16 from aout/wo planes
        dim3 g2(BS_ / 64, DM_ / 64);
        gemm_presplit_kernel<1, 0><<<g2, 256, 0, stream>>>(
            aob, wob, 0, 0, out, DM_, DM_);
    } else {
        // -------- fallback (21 MB workspace) --------
        float* aout = k2 + B_ * KVH_ * M_ * DHH_;
        dim3 g1(BS_ / 64, NW_ / 64);
        gemm_mfma_kernel<3, 2><<<g1, 256, 0, stream>>>(
            x, wq, wk, wv, KOFF_, VOFF_, qkv, NW_, DM_);
        rope_kernel<<<(BS_ * (QH_ + KVH_) * DHH_) / 256, 256, 0, stream>>>(qkv);
        k1k2_kernel<<<32, 256, 0, stream>>>(qkv, k1, k2);
        select4_kernel<false><<<B_ * QH_ * S_ / 16, 256, 0, stream>>>(
            qkv, k1, k2, aout);
        dim3 g2(BS_ / 64, DM_ / 64);
        gemm_mfma_kernel<1, 0><<<g2, 256, 0, stream>>>(
            aout, wo, wo, wo, 1 << 30, 1 << 30, out, DM_, DM_);
    }
}

// Round 11
// 122.377 us; speedup vs baseline: 4.6994x; 1.0928x over previous
//
#include <hip/hip_runtime.h>
#include <hip/hip_bf16.h>
#include <math.h>

// Problem constants (B=2, S=1024, DM=1024, QH=16, KVH=4)
constexpr int B_   = 2;
constexpr int S_   = 1024;
constexpr int DM_  = 1024;
constexpr int QH_  = 16;
constexpr int KVH_ = 4;
constexpr int DH_  = 64;
constexpr int DHH_ = 32;
constexpr int M_   = 32;    // sqrt(S)
constexpr int TOPK_ = 8;
constexpr int BS_  = B_ * S_;                    // 2048
constexpr int NW_  = QH_*DH_ + 2*KVH_*DH_;       // 1536 (q|k|v fused row)
constexpr int KOFF_ = QH_*DH_;                   // 1024
constexpr int VOFF_ = KOFF_ + KVH_*DH_;          // 1280

typedef __attribute__((ext_vector_type(8))) short short8v;   // 8 bf16 (4 VGPR)
typedef __attribute__((ext_vector_type(4))) short short4v;   // 4 bf16 (8B)
typedef __attribute__((ext_vector_type(4))) float float4v;   // MFMA acc

__device__ inline unsigned short bf16_rne(float f) {
    unsigned u = __float_as_uint(f);
    return (unsigned short)((u + 0x7FFFu + ((u >> 16) & 1u)) >> 16);
}
__device__ inline float bf16_back(unsigned short h) {
    return __uint_as_float(((unsigned)h) << 16);
}
__device__ __forceinline__ int swz(int srow) { return ((srow >> 1) & 3) << 4; }

// global -> LDS async copy, 16 B per lane at (ldsbase + lane*16).  CK-style
// address-space casts (uintptr_t round-trip: low 32 bits of a generic LDS
// pointer are the LDS byte offset on gfx9+).
__device__ __forceinline__ void gl_lds16(const void* g, void* l) {
    auto* gp = reinterpret_cast<const __attribute__((address_space(1))) unsigned int*>(
        reinterpret_cast<uintptr_t>(g));
    auto* lp = reinterpret_cast<__attribute__((address_space(3))) unsigned int*>(
        reinterpret_cast<uintptr_t>(l));
    __builtin_amdgcn_global_load_lds(gp, lp, 16, 0, 0);
}

// ---------------------------------------------------------------------------
// Banded "LDS image" layout: matrix [R][1024] f32 -> L bf16 split planes
// stored as band(64 rows) x kc(32) x level x 4096B image, where image byte
// order == the GEMM's swizzled LDS plane byte order.  This lets the GEMM
// stage via global_load_lds (linear dest) while keeping the verified XOR
// swizzle (m173 pattern: bake the swizzle into the stored plane).
// byte(row,col,l) = band*(32*L*4096) + (kc*L+l)*4096 + srow*64
//                   + ((c8*16) ^ swz(srow)) + e*2
// ---------------------------------------------------------------------------
template<int L>
__device__ __forceinline__ void split_banded(const float* __restrict__ src,
                                             int i, char* __restrict__ dst,
                                             int row0)
{
    float4 v = reinterpret_cast<const float4*>(src)[i];
    int row = row0 + (i >> 8);              // 256 float4 per row (K=1024)
    int col = (i & 255) << 2;
    int srow = row & 63;
    char* band = dst + (size_t)(row >> 6) * (32u * L * 4096u);
    int off = ((col >> 5) * L) * 4096 + srow * 64 +
              ((((col & 31) >> 3) * 16) ^ swz(srow)) + (col & 7) * 2;
    float f[4] = {v.x, v.y, v.z, v.w};
#pragma unroll
    for (int l = 0; l < L; ++l) {
        short4v s;
#pragma unroll
        for (int e = 0; e < 4; ++e) {
            unsigned short h = bf16_rne(f[e]);
            s[e] = (short)h;
            f[e] -= bf16_back(h);
        }
        *reinterpret_cast<short4v*>(band + off + l * 4096) = s;
    }
}

// One fused kernel for all split regions (residual chain identical to rounds
// 4/8/9/10 -> bit-identical split values).
__global__ __launch_bounds__(256) void split_all_kernel(
    const float* __restrict__ x,  const float* __restrict__ wq,
    const float* __restrict__ wk, const float* __restrict__ wv,
    const float* __restrict__ wo,
    char* __restrict__ xs, char* __restrict__ wsp, char* __restrict__ wob)
{
    constexpr int E0 = BS_ * DM_ / 4;                 // x
    constexpr int E1 = E0 + KOFF_ * DM_ / 4;          // wq
    constexpr int E2 = E1 + (VOFF_ - KOFF_) * DM_ / 4;// wk
    constexpr int E3 = E2 + (NW_ - VOFF_) * DM_ / 4;  // wv
    constexpr int E4 = E3 + DM_ * DM_ / 4;            // wo
    int i = blockIdx.x * 256 + threadIdx.x;
    if (i < E0)      split_banded<3>(x,  i,      xs,  0);
    else if (i < E1) split_banded<3>(wq, i - E0, wsp, 0);
    else if (i < E2) split_banded<3>(wk, i - E1, wsp, KOFF_);
    else if (i < E3) split_banded<3>(wv, i - E2, wsp, VOFF_);
    else if (i < E4) split_banded<1>(wo, i - E3, wob, 0);
}

// ---------------------------------------------------------------------------
// global_load_lds MFMA GEMM from banded images.  64x64 tile, 4 waves (2x2),
// wave tile 32x32, BK=32, double-buffered LDS, T3-minimum-2-phase: issue
// next tile's 2*LA gload_lds per thread BEFORE compute, one barrier/chunk.
// Round-10 profile showed the reg-staged version LDS-issue-bound (864 LDS
// cyc vs 120 MFMA cyc per kc/block); DMA staging removes the 288-cyc write
// side and the VALU staging entirely.  Fragment reads/MFMA order unchanged
// (bit-identical numerics).  v-col blocks (colBase>=nVstart) use only
// level 0 (value-grade; v never affects selection).
// ---------------------------------------------------------------------------
template<int LEVELS>
__device__ __forceinline__ void stage_tile(const char* a, const char* b,
                                           char* AsB, char* BsB,
                                           int LA, int wvi, int lane)
{
#pragma unroll
    for (int l = 0; l < LEVELS; ++l) if (l < LA) {
        gl_lds16(a + l * 4096 + wvi * 1024 + lane * 16,
                 AsB + l * 4096 + wvi * 1024);
        gl_lds16(b + l * 4096 + wvi * 1024 + lane * 16,
                 BsB + l * 4096 + wvi * 1024);
    }
}

template<int LEVELS, int CROSS>
__global__ __launch_bounds__(256) void gemm_glds_kernel(
    const char* __restrict__ Aimg, const char* __restrict__ Bimg,
    int nVstart, float* __restrict__ C, int N, int K)
{
    __shared__ char As[2][LEVELS * 4096];
    __shared__ char Bs[2][LEVELS * 4096];
    const int tid = threadIdx.x;
    const int rowBase = blockIdx.x * 64;
    const int colBase = blockIdx.y * 64;
    const int lane = tid & 63, wvi = tid >> 6;
    const int wr = wvi >> 1, wc = wvi & 1;     // wave tile origin /32
    const int fr = lane & 15, fk = lane >> 4;  // fragment row, k-group
    const int LA = (colBase >= nVstart) ? 1 : LEVELS;   // block-uniform

    const char* Ab = Aimg + (size_t)blockIdx.x * (32u * LEVELS * 4096u);
    const char* Bb = Bimg + (size_t)blockIdx.y * (32u * LEVELS * 4096u);

    float4v acc[2][2];
#pragma unroll
    for (int mi = 0; mi < 2; ++mi)
#pragma unroll
        for (int ni = 0; ni < 2; ++ni) acc[mi][ni] = (float4v)0.f;

    const int NKC = K >> 5;
    stage_tile<LEVELS>(Ab, Bb, &As[0][0], &Bs[0][0], LA, wvi, lane);
    __syncthreads();                           // drains vmcnt -> tile 0 ready
    int buf = 0;
    for (int kc = 0; kc < NKC; ++kc) {
        if (kc + 1 < NKC)                      // issue next tile (overlaps)
            stage_tile<LEVELS>(Ab + (size_t)(kc + 1) * (LEVELS * 4096),
                               Bb + (size_t)(kc + 1) * (LEVELS * 4096),
                               &As[buf ^ 1][0], &Bs[buf ^ 1][0],
                               LA, wvi, lane);
        short8v aF[LEVELS][2];
#pragma unroll
        for (int l = 0; l < LEVELS; ++l) if (l < LA)
#pragma unroll
            for (int mi = 0; mi < 2; ++mi) {
                int row = wr * 32 + mi * 16 + fr;
                aF[l][mi] = *reinterpret_cast<const short8v*>(
                    &As[buf][l * 4096 + row * 64 + ((fk * 16) ^ swz(row))]);
            }
#pragma unroll
        for (int lb = 0; lb < LEVELS; ++lb) {
            if (lb >= LA) continue;
            short8v bF[2];
#pragma unroll
            for (int ni = 0; ni < 2; ++ni) {
                int row = wc * 32 + ni * 16 + fr;
                bF[ni] = *reinterpret_cast<const short8v*>(
                    &Bs[buf][lb * 4096 + row * 64 + ((fk * 16) ^ swz(row))]);
            }
#pragma unroll
            for (int la = 0; la < LEVELS; ++la) {
                if (la >= LA || la + lb > CROSS) continue;
#pragma unroll
                for (int mi = 0; mi < 2; ++mi)
#pragma unroll
                    for (int ni = 0; ni < 2; ++ni)
                        acc[mi][ni] = __builtin_amdgcn_mfma_f32_16x16x32_bf16(
                            aF[la][mi], bF[ni], acc[mi][ni], 0, 0, 0);
            }
        }
        __syncthreads();                       // drains next-tile loads too
        buf ^= 1;
    }
    // epilogue: C/D layout col=lane&15, row=(lane>>4)*4+j
#pragma unroll
    for (int mi = 0; mi < 2; ++mi)
#pragma unroll
        for (int ni = 0; ni < 2; ++ni) {
            int row0 = rowBase + wr * 32 + mi * 16 + fk * 4;
            int col  = colBase + wc * 32 + ni * 16 + fr;
#pragma unroll
            for (int j = 0; j < 4; ++j)
                C[(size_t)(row0 + j) * N + col] = acc[mi][ni][j];
        }
}

// ---------------------------------------------------------------------------
// Round-8 in-kernel-split GEMM — FALLBACK when ws_size too small.
// ---------------------------------------------------------------------------
template<int LEVELS, int CROSS>
__global__ __launch_bounds__(256) void gemm_mfma_kernel(
    const float* __restrict__ A,
    const float* __restrict__ W0, const float* __restrict__ W1,
    const float* __restrict__ W2, int n1, int n2,
    float* __restrict__ C, int N, int K)
{
    __shared__ short As[LEVELS * 64 * 32];
    __shared__ short Bs[LEVELS * 64 * 32];
    const int tid = threadIdx.x;
    const int rowBase = blockIdx.x * 64;
    const int colBase = blockIdx.y * 64;
    const int lane = tid & 63, wvi = tid >> 6;
    const int wr = wvi >> 1, wc = wvi & 1;
    const int fr = lane & 15, fk = lane >> 4;

    const float* aptr[2]; const float* bptr[2];
    int arow_[2], ac4_[2];
#pragma unroll
    for (int i = 0; i < 2; ++i) {
        int q = i * 256 + tid;
        int row = q >> 3, c4 = q & 7;
        arow_[i] = row; ac4_[i] = c4;
        aptr[i] = A + (size_t)(rowBase + row) * K + c4 * 4;
        int n = colBase + row;
        const float* wrow = (n < n1) ? W0 + (size_t)n * K
                          : (n < n2) ? W1 + (size_t)(n - n1) * K
                                     : W2 + (size_t)(n - n2) * K;
        bptr[i] = wrow + c4 * 4;
    }
    float4 pa[2], pb[2];
#pragma unroll
    for (int i = 0; i < 2; ++i) {
        pa[i] = *reinterpret_cast<const float4*>(aptr[i]);
        pb[i] = *reinterpret_cast<const float4*>(bptr[i]);
    }
    float4v acc[2][2];
#pragma unroll
    for (int mi = 0; mi < 2; ++mi)
#pragma unroll
        for (int ni = 0; ni < 2; ++ni) acc[mi][ni] = (float4v)0.f;

    const int NKC = K >> 5;
    for (int kc = 0; kc < NKC; ++kc) {
#pragma unroll
        for (int i = 0; i < 2; ++i) {
            int row = arow_[i];
            int base = row * 64 + ((ac4_[i] * 8) ^ swz(row));
            float fa[4] = {pa[i].x, pa[i].y, pa[i].z, pa[i].w};
            float fb[4] = {pb[i].x, pb[i].y, pb[i].z, pb[i].w};
#pragma unroll
            for (int l = 0; l < LEVELS; ++l) {
                short4v sa, sb;
#pragma unroll
                for (int e = 0; e < 4; ++e) {
                    unsigned short ha = bf16_rne(fa[e]);
                    unsigned short hb = bf16_rne(fb[e]);
                    sa[e] = (short)ha; sb[e] = (short)hb;
                    fa[e] -= bf16_back(ha);
                    fb[e] -= bf16_back(hb);
                }
                *reinterpret_cast<short4v*>((char*)As + l * 4096 + base) = sa;
                *reinterpret_cast<short4v*>((char*)Bs + l * 4096 + base) = sb;
            }
        }
        __syncthreads();
        if (kc + 1 < NKC) {
#pragma unroll
            for (int i = 0; i < 2; ++i) {
                pa[i] = *reinterpret_cast<const float4*>(aptr[i] + (kc+1)*32);
                pb[i] = *reinterpret_cast<const float4*>(bptr[i] + (kc+1)*32);
            }
        }
        short8v aF[LEVELS][2];
#pragma unroll
        for (int l = 0; l < LEVELS; ++l)
#pragma unroll
            for (int mi = 0; mi < 2; ++mi) {
                int row = wr * 32 + mi * 16 + fr;
                aF[l][mi] = *reinterpret_cast<const short8v*>(
                    (const char*)As + l * 4096 + row * 64 + ((fk * 16) ^ swz(row)));
            }
#pragma unroll
        for (int lb = 0; lb < LEVELS; ++lb) {
            short8v bF[2];
#pragma unroll
            for (int ni = 0; ni < 2; ++ni) {
                int row = wc * 32 + ni * 16 + fr;
                bF[ni] = *reinterpret_cast<const short8v*>(
                    (const char*)Bs + lb * 4096 + row * 64 + ((fk * 16) ^ swz(row)));
            }
#pragma unroll
            for (int la = 0; la < LEVELS; ++la) {
                if (la + lb > CROSS) continue;
#pragma unroll
                for (int mi = 0; mi < 2; ++mi)
#pragma unroll
                    for (int ni = 0; ni < 2; ++ni)
                        acc[mi][ni] = __builtin_amdgcn_mfma_f32_16x16x32_bf16(
                            aF[la][mi], bF[ni], acc[mi][ni], 0, 0, 0);
            }
        }
        __syncthreads();
    }
#pragma unroll
    for (int mi = 0; mi < 2; ++mi)
#pragma unroll
        for (int ni = 0; ni < 2; ++ni) {
            int row0 = rowBase + wr * 32 + mi * 16 + fk * 4;
            int col  = colBase + wc * 32 + ni * 16 + fr;
#pragma unroll
            for (int j = 0; j < 4; ++j)
                C[(size_t)(row0 + j) * N + col] = acc[mi][ni][j];
        }
}

// ---------------------------------------------------------------------------
// RoPE in-place, bit-matching the numpy f32 reference.
// ---------------------------------------------------------------------------
__global__ __launch_bounds__(256) void rope_kernel(float* __restrict__ qkv)
{
    int id = blockIdx.x * 256 + threadIdx.x;   // BS * 20 * 32 threads
    int d  = id & 31;
    int r  = id >> 5;
    int h  = r % (QH_ + KVH_);
    int bs = r / (QH_ + KVH_);
    int s  = bs & (S_ - 1);
    float* base = qkv + (size_t)bs * NW_ +
                  (h < QH_ ? h * DH_ : KOFF_ + (h - QH_) * DH_);
    double e = (double)d * (1.0 / 32.0);
    float pf = (float)pow(10000.0, e);         // == correctly-rounded powf
    float inv_freq = __fdiv_rn(1.0f, pf);      // numpy's 2nd f32 rounding
    float ang = __fmul_rn((float)s, inv_freq);
    double sn64, cs64;
    sincos((double)ang, &sn64, &cs64);
    float cs = (float)cs64;
    float sn = (float)sn64;
    float x1 = base[d];
    float x2 = base[d + DHH_];
    base[d]        = __fadd_rn(__fmul_rn(x1, cs), __fmul_rn(-x2, sn));
    base[d + DHH_] = __fadd_rn(__fmul_rn(x2, cs), __fmul_rn(x1, sn));
}

// ---------------------------------------------------------------------------
// k1/k2 grid sums: f64 accum, f32 store.  32 blocks.
// ---------------------------------------------------------------------------
__global__ __launch_bounds__(256) void k1k2_kernel(
    const float* __restrict__ qkv, float* __restrict__ k1,
    float* __restrict__ k2)
{
    int blk   = blockIdx.x;
    int bkv   = blk >> 2;
    int chunk = blk & 3;
    int b = bkv >> 2, kv = bkv & 3;
    int tid = threadIdx.x;
    int d  = tid & 31;
    int m  = chunk * 8 + (tid >> 5);
    const float* kbase = qkv + (size_t)b * S_ * NW_ + KOFF_ + kv * DH_;
    double s1 = 0., s2 = 0.;
    for (int mc = 0; mc < M_; ++mc) {
        s1 += (double)kbase[(size_t)(m * M_ + mc) * NW_ + d];
        s2 += (double)kbase[(size_t)(mc * M_ + m) * NW_ + DHH_ + d];
    }
    k1[((b * KVH_ + kv) * M_ + m) * DHH_ + d] = (float)s1;
    k2[((b * KVH_ + kv) * M_ + m) * DHH_ + d] = (float)s2;
}

// ---------------------------------------------------------------------------
// Select + attention, bitonic, 4 s-problems per wave (round-10 verified).
// OUTMODE 0: f32 flat (fallback);  1: bf16 banded image (for glds out GEMM).
// ---------------------------------------------------------------------------
template<int OUTMODE>
__global__ __launch_bounds__(256) void select4_kernel(
    const float* __restrict__ qkv,
    const float* __restrict__ k1g, const float* __restrict__ k2g,
    void* __restrict__ aout)
{
    __shared__ float k1s[M_][DHH_ + 1];
    __shared__ float k2s[M_][DHH_ + 1];
    __shared__ float qs[16][DH_];

    const int tid = threadIdx.x;
    const int bh  = blockIdx.x >> 6;           // 64 blocks per (b,h)
    const int s0  = (blockIdx.x & 63) << 4;
    const int b   = bh >> 4;
    const int h   = bh & 15;
    const int kv  = h >> 2;

    const int kbase = (b * KVH_ + kv) * M_ * DHH_;
    for (int i = tid; i < M_ * DHH_; i += 256) {
        k1s[i >> 5][i & 31] = k1g[kbase + i];
        k2s[i >> 5][i & 31] = k2g[kbase + i];
    }
    for (int i = tid; i < 16 * DH_; i += 256) {
        int r = i >> 6;
        qs[r][i & 63] = qkv[(size_t)(b * S_ + s0 + r) * NW_ + h * DH_ + (i & 63)];
    }
    const int w = tid >> 6, lane = tid & 63;
    __syncthreads();

    const int m = lane & 31;
    const bool hi = lane >= 32;
    const float* krow = hi ? &k2s[m][0] : &k1s[m][0];
    const int qoff = hi ? DHH_ : 0;

    float v1[4]; int i1[4];
#pragma unroll
    for (int u = 0; u < 4; ++u) { v1[u] = 0.f; i1[u] = m; }
#pragma unroll
    for (int d = 0; d < DHH_; ++d) {
        float kd = krow[d];
#pragma unroll
        for (int u = 0; u < 4; ++u)
            v1[u] = fmaf(qs[w * 4 + u][qoff + d], kd, v1[u]);
    }

    const int l5 = lane & 31;
#pragma unroll
    for (int k = 2; k <= 32; k <<= 1) {
#pragma unroll
        for (int j = k >> 1; j > 0; j >>= 1) {
            float ov[4]; int oi[4];
#pragma unroll
            for (int u = 0; u < 4; ++u) {
                ov[u] = __shfl_xor(v1[u], j);
                oi[u] = __shfl_xor(i1[u], j);
            }
            const bool dirD  = ((l5 & k) == 0);
            const bool lower = ((lane & j) == 0);
#pragma unroll
            for (int u = 0; u < 4; ++u) {
                bool gt = (v1[u] > ov[u]) || (v1[u] == ov[u] && i1[u] < oi[u]);
                if (gt != (dirD == lower)) { v1[u] = ov[u]; i1[u] = oi[u]; }
            }
        }
    }

    float v2[4]; int c2[4];
#pragma unroll
    for (int u = 0; u < 4; ++u) {
        float av = __shfl(v1[u], lane >> 3);
        float bv = __shfl(v1[u], 32 + (lane & 7));
        v2[u] = av + bv; c2[u] = lane;
    }
#pragma unroll
    for (int k = 2; k <= 64; k <<= 1) {
#pragma unroll
        for (int j = k >> 1; j > 0; j >>= 1) {
            float ov[4]; int oc[4];
#pragma unroll
            for (int u = 0; u < 4; ++u) {
                ov[u] = __shfl_xor(v2[u], j);
                oc[u] = __shfl_xor(c2[u], j);
            }
            const bool dirD  = ((lane & k) == 0);
            const bool lower = ((lane & j) == 0);
#pragma unroll
            for (int u = 0; u < 4; ++u) {
                bool gt = (v2[u] > ov[u]) || (v2[u] == ov[u] && c2[u] < oc[u]);
                if (gt != (dirD == lower)) { v2[u] = ov[u]; c2[u] = oc[u]; }
            }
        }
    }

    const float* vbase = qkv + (size_t)b * S_ * NW_ + VOFF_ + kv * DH_ + lane;
#pragma unroll
    for (int u = 0; u < 4; ++u) {
        float vmax = __shfl(v2[u], 0);
        float e = (lane < 8) ? expf((v2[u] - vmax) * 0.125f) : 0.f;
        float sum = e;
#pragma unroll
        for (int msk = 1; msk <= 4; msk <<= 1) sum += __shfl_xor(sum, msk);
        float wn = e / sum;
        float o = 0.f;
#pragma unroll
        for (int t = 0; t < TOPK_; ++t) {
            float wt  = __shfl(wn, t);
            int   ct  = __shfl(c2[u], t);
            int   row = __shfl(i1[u], ct >> 3);
            int   col = __shfl(i1[u], 32 + (ct & 7));
            o = fmaf(wt, vbase[(size_t)(row * M_ + col) * NW_], o);
        }
        int orow = b * S_ + s0 + w * 4 + u;
        int ocol = h * DH_ + lane;
        if (OUTMODE == 1) {
            int srow = orow & 63;
            size_t byteoff = (size_t)(orow >> 6) * (32u * 4096u)
                           + (size_t)(ocol >> 5) * 4096 + srow * 64
                           + ((((ocol & 31) >> 3) * 16) ^ swz(srow))
                           + (ocol & 7) * 2;
            *reinterpret_cast<short*>((char*)aout + byteoff) = (short)bf16_rne(o);
        } else {
            ((float*)aout)[(size_t)orow * (QH_ * DH_) + ocol] = o;
        }
    }
}

// ---------------------------------------------------------------------------
extern "C" void kernel_launch(void* const* d_in, const int* in_sizes, int n_in,
                              void* d_out, int out_size, void* d_ws,
                              size_t ws_size, hipStream_t stream)
{
    const float* x  = (const float*)d_in[0];
    const float* wq = (const float*)d_in[1];
    const float* wk = (const float*)d_in[2];
    const float* wv = (const float*)d_in[3];
    const float* wo = (const float*)d_in[4];
    float* out = (float*)d_out;

    float* wsf = (float*)d_ws;
    float* qkv = wsf;                                    // 2048*1536 f32
    float* k1  = qkv + (size_t)BS_ * NW_;                // 8192 f32
    float* k2  = k1 + B_ * KVH_ * M_ * DHH_;             // 8192 f32

    const bool fast = ws_size >= 40960000ull;

    if (fast) {
        char* xs  = (char*)(k2 + B_ * KVH_ * M_ * DHH_); // 12.58 MB image
        char* wsp = xs  + (size_t)3 * BS_ * DM_ * 2;     //  9.44 MB image
        char* wob = wsp + (size_t)3 * NW_ * DM_ * 2;     //  2.10 MB image
        char* aob = wob + (size_t)DM_ * DM_ * 2;         //  4.19 MB image

        // 0) all split planes (banded-swizzled images) in one launch
        constexpr int NSLOT = (BS_*DM_ + KOFF_*DM_ + (VOFF_-KOFF_)*DM_ +
                               (NW_-VOFF_)*DM_ + DM_*DM_) / 4;
        split_all_kernel<<<(NSLOT + 255) / 256, 256, 0, stream>>>(
            x, wq, wk, wv, wo, xs, wsp, wob);

        // 1) fused qkv GEMM via global_load_lds (v-blocks value-grade)
        dim3 g1(BS_ / 64, NW_ / 64);
        gemm_glds_kernel<3, 2><<<g1, 256, 0, stream>>>(
            xs, wsp, VOFF_, qkv, NW_, DM_);
        // 2) RoPE
        rope_kernel<<<(BS_ * (QH_ + KVH_) * DHH_) / 256, 256, 0, stream>>>(qkv);
        // 3) k1/k2
        k1k2_kernel<<<32, 256, 0, stream>>>(qkv, k1, k2);
        // 4) select, 4 s per wave (writes bf16 banded aout)
        select4_kernel<1><<<B_ * QH_ * S_ / 16, 256, 0, stream>>>(
            qkv, k1, k2, aob);
        // 5) output GEMM via global_load_lds
        dim3 g2(BS_ / 64, DM_ / 64);
        gemm_glds_kernel<1, 0><<<g2, 256, 0, stream>>>(
            aob, wob, 1 << 30, out, DM_, DM_);
    } else {
        // -------- fallback (21 MB workspace), round-8 proven path --------
        float* aout = k2 + B_ * KVH_ * M_ * DHH_;
        dim3 g1(BS_ / 64, NW_ / 64);
        gemm_mfma_kernel<3, 2><<<g1, 256, 0, stream>>>(
            x, wq, wk, wv, KOFF_, VOFF_, qkv, NW_, DM_);
        rope_kernel<<<(BS_ * (QH_ + KVH_) * DHH_) / 256, 256, 0, stream>>>(qkv);
        k1k2_kernel<<<32, 256, 0, stream>>>(qkv, k1, k2);
        select4_kernel<0><<<B_ * QH_ * S_ / 16, 256, 0, stream>>>(
            qkv, k1, k2, aout);
        dim3 g2(BS_ / 64, DM_ / 64);
        gemm_mfma_kernel<1, 0><<<g2, 256, 0, stream>>>(
            aout, wo, wo, wo, 1 << 30, 1 << 30, out, DM_, DM_);
    }
}